// Round 4
// baseline (2372.538 us; speedup 1.0000x reference)
//
#include <hip/hip_runtime.h>
#include <hip/hip_bf16.h>
#include <math.h>

#define N_NODES 100000
#define N_EDGES 1600000
#define N_REL   500
#define DIM     128
#define NHEAD   8
#define DFF     512
#define ALPHA   0.15f
#define SLOPE   0.2f
#define LN_EPS  1e-5f

typedef unsigned short u16;
typedef unsigned int   u32;

// internal bf16 storage helpers (workspace-only; I/O is fp32)
__device__ __forceinline__ float bf2f(u16 u) {
    return __uint_as_float(((u32)u) << 16);
}
__device__ __forceinline__ u16 f2bf(float f) {
    __hip_bfloat16 b = __float2bfloat16(f);
    return *reinterpret_cast<u16*>(&b);
}

// ---------------- zero an int buffer (graph-capture-safe memset) ------------
__global__ void zero_k(int* __restrict__ p, int n) {
    int i = blockIdx.x * blockDim.x + threadIdx.x;
    if (i < n) p[i] = 0;
}

// ---------------- LayerNorm 1 : h = LN(ent_feat)  (fp32 in/out) -------------
__global__ __launch_bounds__(128) void ln1_k(const float* __restrict__ x,
        const float* __restrict__ g, const float* __restrict__ b,
        float* __restrict__ h) {
    const int n = blockIdx.x, t = threadIdx.x;
    const float v = x[n * DIM + t];
    float s = v, q = v * v;
#pragma unroll
    for (int off = 32; off > 0; off >>= 1) {
        s += __shfl_xor(s, off, 64);
        q += __shfl_xor(q, off, 64);
    }
    __shared__ float ss[2], qq[2];
    if ((t & 63) == 0) { ss[t >> 6] = s; qq[t >> 6] = q; }
    __syncthreads();
    s = ss[0] + ss[1]; q = qq[0] + qq[1];
    const float mu  = s * (1.0f / 128.0f);
    const float var = q * (1.0f / 128.0f) - mu * mu;
    const float rs  = rsqrtf(fmaxf(var, 0.f) + LN_EPS);
    h[n * DIM + t] = (v - mu) * rs * g[t] + b[t];
}

// --------- feat0 = h @ W_ent (bf16 internal out) ; eh/et attn dots ----------
// block = 256 threads, 8 nodes/block, thread -> (node = t/32, 4 cols)
__global__ __launch_bounds__(256) void proj_k(const float* __restrict__ h,
        const float* __restrict__ W,       // W_ent [128x128] fp32
        const float* __restrict__ attn_h, const float* __restrict__ attn_t,
        u16* __restrict__ feat0, float* __restrict__ eh, float* __restrict__ et) {
    __shared__ float hs[8][DIM];
    const int t  = threadIdx.x;
    const int n0 = blockIdx.x * 8;
    {
        const int r = t >> 5;
        const int c = (t & 31) * 4;
        *(float4*)&hs[r][c] = *(const float4*)&h[(n0 + r) * DIM + c];
    }
    __syncthreads();
    const int node = t >> 5;
    const int j0   = (t & 31) * 4;
    float4 acc = {0.f, 0.f, 0.f, 0.f};
    for (int d = 0; d < DIM; d += 4) {
        const float4 h4 = *(const float4*)&hs[node][d];
        const float4 w0 = *(const float4*)&W[(d + 0) * DIM + j0];
        const float4 w1 = *(const float4*)&W[(d + 1) * DIM + j0];
        const float4 w2 = *(const float4*)&W[(d + 2) * DIM + j0];
        const float4 w3 = *(const float4*)&W[(d + 3) * DIM + j0];
        acc.x += h4.x * w0.x + h4.y * w1.x + h4.z * w2.x + h4.w * w3.x;
        acc.y += h4.x * w0.y + h4.y * w1.y + h4.z * w2.y + h4.w * w3.y;
        acc.z += h4.x * w0.z + h4.y * w1.z + h4.z * w2.z + h4.w * w3.z;
        acc.w += h4.x * w0.w + h4.y * w1.w + h4.z * w2.w + h4.w * w3.w;
    }
    const int n = n0 + node;
    ushort4 fo;
    fo.x = f2bf(acc.x); fo.y = f2bf(acc.y); fo.z = f2bf(acc.z); fo.w = f2bf(acc.w);
    *(ushort4*)&feat0[n * DIM + j0] = fo;
    const float4 ah = *(const float4*)&attn_h[j0];
    const float4 at = *(const float4*)&attn_t[j0];
    float ph = acc.x * ah.x + acc.y * ah.y + acc.z * ah.z + acc.w * ah.w;
    float pt = acc.x * at.x + acc.y * at.y + acc.z * at.z + acc.w * at.w;
    ph += __shfl_xor(ph, 1, 64); ph += __shfl_xor(ph, 2, 64);
    pt += __shfl_xor(pt, 1, 64); pt += __shfl_xor(pt, 2, 64);
    if ((t & 3) == 0) {
        const int head = (t & 31) >> 2;
        eh[n * NHEAD + head] = ph;
        et[n * NHEAD + head] = pt;
    }
}

// ---------------- er[r][head] = ((rel_feat @ W_rel) * attn_r).sum ----------
__global__ __launch_bounds__(128) void rel_k(const float* __restrict__ rel_feat,
        const float* __restrict__ W,
        const float* __restrict__ attn_r, float* __restrict__ er) {
    __shared__ float rf[DIM];
    __shared__ float pr[DIM];
    const int r = blockIdx.x, t = threadIdx.x;
    rf[t] = rel_feat[r * DIM + t];
    __syncthreads();
    float acc = 0.f;
    for (int d = 0; d < DIM; ++d) acc += rf[d] * W[d * DIM + t];
    pr[t] = acc * attn_r[t];
    __syncthreads();
    if (t < NHEAD) {
        float s = 0.f;
        for (int i = 0; i < 16; ++i) s += pr[t * 16 + i];
        er[r * NHEAD + t] = s;
    }
}

// ---------------- CSR build: histogram, scan, scatter ----------------------
__global__ void count_k(const int* __restrict__ dst, int* __restrict__ counts) {
    int e = blockIdx.x * blockDim.x + threadIdx.x;
    if (e < N_EDGES) atomicAdd(&counts[dst[e]], 1);
}

// single-wave exclusive scan, 8x64 values per outer iteration
__global__ __launch_bounds__(64) void scan_k(const int* __restrict__ counts,
        int* __restrict__ offsets, int* __restrict__ cursor, int n) {
    const int lane = threadIdx.x;
    int base = 0;
    for (int start = 0; start < n; start += 512) {
        int v[8];
#pragma unroll
        for (int j = 0; j < 8; ++j) {
            const int i = start + j * 64 + lane;
            v[j] = (i < n) ? counts[i] : 0;
        }
#pragma unroll
        for (int j = 0; j < 8; ++j) {
            int incl = v[j];
#pragma unroll
            for (int off = 1; off < 64; off <<= 1) {
                const int tt = __shfl_up(incl, off, 64);
                if (lane >= off) incl += tt;
            }
            const int i = start + j * 64 + lane;
            const int excl = base + incl - v[j];
            if (i < n) { offsets[i] = excl; cursor[i] = excl; }
            base += __shfl(incl, 63, 64);
        }
    }
    if (lane == 0) offsets[n] = base;
}

__global__ void scatter_k(const int* __restrict__ src, const int* __restrict__ dst,
        const int* __restrict__ etype,
        const float* __restrict__ eh, const float* __restrict__ et,
        const float* __restrict__ er,
        int* __restrict__ cursor, int* __restrict__ csr_src,
        float* __restrict__ csr_a) {
    const int e = blockIdx.x * blockDim.x + threadIdx.x;
    if (e >= N_EDGES) return;
    const int s = src[e], d = dst[e], r = etype[e];
    const float4 h0 = *(const float4*)&eh[s * NHEAD];
    const float4 h1 = *(const float4*)&eh[s * NHEAD + 4];
    const float4 t0 = *(const float4*)&et[d * NHEAD];
    const float4 t1 = *(const float4*)&et[d * NHEAD + 4];
    const float4 r0 = *(const float4*)&er[r * NHEAD];
    const float4 r1 = *(const float4*)&er[r * NHEAD + 4];
    float4 a0, a1;
    a0.x = h0.x + t0.x + r0.x; a0.y = h0.y + t0.y + r0.y;
    a0.z = h0.z + t0.z + r0.z; a0.w = h0.w + t0.w + r0.w;
    a1.x = h1.x + t1.x + r1.x; a1.y = h1.y + t1.y + r1.y;
    a1.z = h1.z + t1.z + r1.z; a1.w = h1.w + t1.w + r1.w;
    a0.x = a0.x > 0.f ? a0.x : SLOPE * a0.x;
    a0.y = a0.y > 0.f ? a0.y : SLOPE * a0.y;
    a0.z = a0.z > 0.f ? a0.z : SLOPE * a0.z;
    a0.w = a0.w > 0.f ? a0.w : SLOPE * a0.w;
    a1.x = a1.x > 0.f ? a1.x : SLOPE * a1.x;
    a1.y = a1.y > 0.f ? a1.y : SLOPE * a1.y;
    a1.z = a1.z > 0.f ? a1.z : SLOPE * a1.z;
    a1.w = a1.w > 0.f ? a1.w : SLOPE * a1.w;
    const int pos = atomicAdd(&cursor[d], 1);
    if (pos < 0 || pos >= N_EDGES) return;   // defensive
    csr_src[pos] = s;
    *(float4*)&csr_a[pos * NHEAD]     = a0;
    *(float4*)&csr_a[pos * NHEAD + 4] = a1;
}

// --------- edge softmax over each node's incoming edges (in-place) ---------
// one wave per node; lane -> (edge slot = lane/8, head = lane%8)
__global__ __launch_bounds__(64) void softmax_k(const int* __restrict__ offsets,
        float* __restrict__ csr_a) {
    const int n = blockIdx.x;
    const int beg = offsets[n], end = offsets[n + 1];
    if (beg >= end) return;
    const int lane = threadIdx.x;
    const int k  = lane & 7;
    const int eo = lane >> 3;
    float m = -1e30f;
    for (int e = beg + eo; e < end; e += 8)
        m = fmaxf(m, csr_a[e * NHEAD + k]);
    m = fmaxf(m, __shfl_xor(m, 8, 64));
    m = fmaxf(m, __shfl_xor(m, 16, 64));
    m = fmaxf(m, __shfl_xor(m, 32, 64));
    float ssum = 0.f;
    for (int e = beg + eo; e < end; e += 8) {
        const float ex = expf(csr_a[e * NHEAD + k] - m);
        csr_a[e * NHEAD + k] = ex;
        ssum += ex;
    }
    ssum += __shfl_xor(ssum, 8, 64);
    ssum += __shfl_xor(ssum, 16, 64);
    ssum += __shfl_xor(ssum, 32, 64);
    const float inv = 1.f / fmaxf(ssum, 1e-20f);
    for (int e = beg + eo; e < end; e += 8)
        csr_a[e * NHEAD + k] *= inv;
}

// ---------------- one PPR diffusion hop (bf16 internal f buffers) ----------
// one wave per node; lane covers dims 2*lane, 2*lane+1 ; head = lane/8
// NOTE: f_in and feat0 may alias (hop 1) -> no __restrict__ on them.
__global__ __launch_bounds__(64) void hop_k(const u16* f_in,
        u16* __restrict__ f_out, const u16* feat0,
        const int* __restrict__ offsets, const int* __restrict__ csr_src,
        const float* __restrict__ csr_a) {
    const int n    = blockIdx.x;
    const int lane = threadIdx.x;
    const int beg = offsets[n], end = offsets[n + 1];
    const int hsel = lane >> 3;
    const int d2   = lane << 1;
    float2 acc = {0.f, 0.f};
    for (int e = beg; e < end; ++e) {
        int s0 = csr_src[e];
        s0 = s0 < 0 ? 0 : (s0 >= N_NODES ? N_NODES - 1 : s0);  // defensive
        const float a0 = csr_a[e * NHEAD + hsel];
        const ushort2 w0 = *(const ushort2*)&f_in[s0 * DIM + d2];
        acc.x += a0 * bf2f(w0.x);
        acc.y += a0 * bf2f(w0.y);
    }
    const ushort2 p = *(const ushort2*)&feat0[n * DIM + d2];
    const float ox = (1.f - ALPHA) * acc.x + ALPHA * bf2f(p.x);
    const float oy = (1.f - ALPHA) * acc.y + ALPHA * bf2f(p.y);
    ushort2 o; o.x = f2bf(ox); o.y = f2bf(oy);
    *(ushort2*)&f_out[n * DIM + d2] = o;
}

// ---------------- FFN sublayer + residuals, fp32 output --------------------
// block = 256 threads, 16 nodes/block. rst recomputed in phase C (no buffer).
__global__ __launch_bounds__(256) void ffn_k(const u16* __restrict__ f,
        const float* __restrict__ h,
        const float* __restrict__ g2, const float* __restrict__ b2ln,
        const float* __restrict__ W1, const float* __restrict__ b1,
        const float* __restrict__ W2, const float* __restrict__ b2,
        float* __restrict__ out) {
    __shared__ float ys[16][DIM];
    __shared__ float zs[16][DFF];
    __shared__ float red[16][16];
    __shared__ float red2[16][16];
    __shared__ float mu_s[16], rs_s[16];
    const int t  = threadIdx.x;
    const int n0 = blockIdx.x * 16;

    // Phase A: rst = f + h ; LN2 stats ; y into LDS
    const int an = t >> 4;
    const int ap = t & 15;
    float rv[8];
    {
        const int base = (n0 + an) * DIM + ap * 8;
        const ushort4 fa4 = *(const ushort4*)&f[base];
        const ushort4 fb4 = *(const ushort4*)&f[base + 4];
        const float4 ha = *(const float4*)&h[base];
        const float4 hb = *(const float4*)&h[base + 4];
        rv[0] = bf2f(fa4.x) + ha.x;
        rv[1] = bf2f(fa4.y) + ha.y;
        rv[2] = bf2f(fa4.z) + ha.z;
        rv[3] = bf2f(fa4.w) + ha.w;
        rv[4] = bf2f(fb4.x) + hb.x;
        rv[5] = bf2f(fb4.y) + hb.y;
        rv[6] = bf2f(fb4.z) + hb.z;
        rv[7] = bf2f(fb4.w) + hb.w;
        float s = 0.f, q = 0.f;
#pragma unroll
        for (int i = 0; i < 8; ++i) { s += rv[i]; q += rv[i] * rv[i]; }
        red[an][ap] = s; red2[an][ap] = q;
    }
    __syncthreads();
    if (t < 16) {
        float s = 0.f, q = 0.f;
#pragma unroll
        for (int i = 0; i < 16; ++i) { s += red[t][i]; q += red2[t][i]; }
        const float mu  = s * (1.0f / 128.0f);
        const float var = q * (1.0f / 128.0f) - mu * mu;
        mu_s[t] = mu;
        rs_s[t] = rsqrtf(fmaxf(var, 0.f) + LN_EPS);
    }
    __syncthreads();
    {
        const float mu = mu_s[an], rs = rs_s[an];
#pragma unroll
        for (int i = 0; i < 8; ++i) {
            const int c = ap * 8 + i;
            ys[an][c] = (rv[i] - mu) * rs * g2[c] + b2ln[c];
        }
    }
    __syncthreads();

    // Phase B: z = relu(y @ W1 + b1) -> LDS
    {
        const int c0 = (t & 127) * 4;
        const int nh = (t >> 7) * 8;
        float4 accB[8];
        const float4 bb = *(const float4*)&b1[c0];
#pragma unroll
        for (int i = 0; i < 8; ++i) { accB[i] = bb; }
        for (int d = 0; d < DIM; d += 4) {
            const float4 w0 = *(const float4*)&W1[(d + 0) * DFF + c0];
            const float4 w1v = *(const float4*)&W1[(d + 1) * DFF + c0];
            const float4 w2v = *(const float4*)&W1[(d + 2) * DFF + c0];
            const float4 w3v = *(const float4*)&W1[(d + 3) * DFF + c0];
#pragma unroll
            for (int i = 0; i < 8; ++i) {
                const float4 y4 = *(const float4*)&ys[nh + i][d];
                accB[i].x += y4.x * w0.x + y4.y * w1v.x + y4.z * w2v.x + y4.w * w3v.x;
                accB[i].y += y4.x * w0.y + y4.y * w1v.y + y4.z * w2v.y + y4.w * w3v.y;
                accB[i].z += y4.x * w0.z + y4.y * w1v.z + y4.z * w2v.z + y4.w * w3v.z;
                accB[i].w += y4.x * w0.w + y4.y * w1v.w + y4.z * w2v.w + y4.w * w3v.w;
            }
        }
#pragma unroll
        for (int i = 0; i < 8; ++i) {
            float4 z;
            z.x = fmaxf(accB[i].x, 0.f); z.y = fmaxf(accB[i].y, 0.f);
            z.z = fmaxf(accB[i].z, 0.f); z.w = fmaxf(accB[i].w, 0.f);
            *(float4*)&zs[nh + i][c0] = z;
        }
    }
    __syncthreads();

    // Phase C: out = z @ W2 + b2 + (f + h)   (fp32 out)
    for (int half = 0; half < 2; ++half) {
        const int node = half * 8 + (t >> 5);
        const int c0   = (t & 31) * 4;
        float4 acc = *(const float4*)&b2[c0];
        for (int d = 0; d < DFF; d += 4) {
            const float4 z4 = *(const float4*)&zs[node][d];
            const float4 w0 = *(const float4*)&W2[(d + 0) * DIM + c0];
            const float4 w1v = *(const float4*)&W2[(d + 1) * DIM + c0];
            const float4 w2v = *(const float4*)&W2[(d + 2) * DIM + c0];
            const float4 w3v = *(const float4*)&W2[(d + 3) * DIM + c0];
            acc.x += z4.x * w0.x + z4.y * w1v.x + z4.z * w2v.x + z4.w * w3v.x;
            acc.y += z4.x * w0.y + z4.y * w1v.y + z4.z * w2v.y + z4.w * w3v.y;
            acc.z += z4.x * w0.z + z4.y * w1v.z + z4.z * w2v.z + z4.w * w3v.z;
            acc.w += z4.x * w0.w + z4.y * w1v.w + z4.z * w2v.w + z4.w * w3v.w;
        }
        const int gbase = (n0 + node) * DIM + c0;
        const ushort4 fu = *(const ushort4*)&f[gbase];
        const float4  hr = *(const float4*)&h[gbase];
        float4 o;
        o.x = acc.x + bf2f(fu.x) + hr.x;
        o.y = acc.y + bf2f(fu.y) + hr.y;
        o.z = acc.z + bf2f(fu.z) + hr.z;
        o.w = acc.w + bf2f(fu.w) + hr.w;
        *(float4*)&out[gbase] = o;
    }
}

// ---------------------------------------------------------------------------
extern "C" void kernel_launch(void* const* d_in, const int* in_sizes, int n_in,
                              void* d_out, int out_size, void* d_ws, size_t ws_size,
                              hipStream_t stream) {
    const float* ent_feat = (const float*)d_in[0];
    const float* rel_feat = (const float*)d_in[1];
    const int*   src      = (const int*)d_in[2];
    const int*   dst      = (const int*)d_in[3];
    const int*   e_type   = (const int*)d_in[4];
    const float* ln1_g    = (const float*)d_in[5];
    const float* ln1_b    = (const float*)d_in[6];
    const float* W_ent    = (const float*)d_in[7];
    const float* W_rel    = (const float*)d_in[8];
    const float* attn_h   = (const float*)d_in[9];
    const float* attn_t   = (const float*)d_in[10];
    const float* attn_r   = (const float*)d_in[11];
    const float* ln2_g    = (const float*)d_in[12];
    const float* ln2_b    = (const float*)d_in[13];
    const float* W1       = (const float*)d_in[14];
    const float* b1       = (const float*)d_in[15];
    const float* W2       = (const float*)d_in[16];
    const float* b2       = (const float*)d_in[17];
    float* out = (float*)d_out;

    char* ws = (char*)d_ws;
    size_t used = 0;
    auto alloc = [&](size_t bytes) -> char* {
        char* p = ws + used;
        used += (bytes + 255) & ~(size_t)255;
        return p;
    };
    float* h       = (float*)alloc((size_t)N_NODES * DIM * 4);   // 51.2 MB
    u16*   feat0   = (u16*)  alloc((size_t)N_NODES * DIM * 2);   // 25.6 MB
    u16*   fA      = (u16*)  alloc((size_t)N_NODES * DIM * 2);   // 25.6 MB
    u16*   fB      = (u16*)  alloc((size_t)N_NODES * DIM * 2);   // 25.6 MB
    float* csr_a   = (float*)alloc((size_t)N_EDGES * NHEAD * 4); // 51.2 MB
    float* eh      = (float*)alloc((size_t)N_NODES * NHEAD * 4);
    float* et      = (float*)alloc((size_t)N_NODES * NHEAD * 4);
    int*   csr_src = (int*)  alloc((size_t)N_EDGES * 4);
    int*   counts  = (int*)  alloc((size_t)N_NODES * 4);
    int*   offsets = (int*)  alloc((size_t)(N_NODES + 1) * 4);
    int*   cursor  = (int*)  alloc((size_t)N_NODES * 4);
    float* er      = (float*)alloc((size_t)N_REL * NHEAD * 4);

    // Defensive: if workspace too small, skip (diagnostic: absmax == max|ref|)
    if (used > ws_size) return;

    ln1_k<<<N_NODES, 128, 0, stream>>>(ent_feat, ln1_g, ln1_b, h);
    proj_k<<<N_NODES / 8, 256, 0, stream>>>(h, W_ent, attn_h, attn_t, feat0, eh, et);
    rel_k<<<N_REL, 128, 0, stream>>>(rel_feat, W_rel, attn_r, er);

    zero_k<<<(N_NODES + 255) / 256, 256, 0, stream>>>(counts, N_NODES);
    count_k<<<(N_EDGES + 255) / 256, 256, 0, stream>>>(dst, counts);
    scan_k<<<1, 64, 0, stream>>>(counts, offsets, cursor, N_NODES);
    scatter_k<<<(N_EDGES + 255) / 256, 256, 0, stream>>>(src, dst, e_type, eh, et, er,
                                                         cursor, csr_src, csr_a);
    softmax_k<<<N_NODES, 64, 0, stream>>>(offsets, csr_a);

    // 5 PPR hops: feat0 -> fA -> fB -> fA -> fB -> fA
    hop_k<<<N_NODES, 64, 0, stream>>>(feat0, fA, feat0, offsets, csr_src, csr_a);
    hop_k<<<N_NODES, 64, 0, stream>>>(fA, fB, feat0, offsets, csr_src, csr_a);
    hop_k<<<N_NODES, 64, 0, stream>>>(fB, fA, feat0, offsets, csr_src, csr_a);
    hop_k<<<N_NODES, 64, 0, stream>>>(fA, fB, feat0, offsets, csr_src, csr_a);
    hop_k<<<N_NODES, 64, 0, stream>>>(fB, fA, feat0, offsets, csr_src, csr_a);

    // FFN + residuals
    ffn_k<<<N_NODES / 16, 256, 0, stream>>>(fA, h, ln2_g, ln2_b, W1, b1, W2, b2,
                                            out);
}

// Round 5
// 1527.338 us; speedup vs baseline: 1.5534x; 1.5534x over previous
//
#include <hip/hip_runtime.h>
#include <hip/hip_bf16.h>
#include <math.h>

#define N_NODES 100000
#define N_EDGES 1600000
#define N_REL   500
#define DIM     128
#define NHEAD   8
#define DFF     512
#define ALPHA   0.15f
#define SLOPE   0.2f
#define LN_EPS  1e-5f

typedef unsigned short u16;
typedef unsigned int   u32;

typedef __attribute__((ext_vector_type(8))) short  bf16x8;   // MFMA A/B frag
typedef __attribute__((ext_vector_type(4))) float  f32x4;    // MFMA C/D frag

__device__ __forceinline__ float bf2f(u16 u) {
    return __uint_as_float(((u32)u) << 16);
}
__device__ __forceinline__ u16 f2bf(float f) {
    __hip_bfloat16 b = __float2bfloat16(f);
    return *reinterpret_cast<u16*>(&b);
}

// ---------------- zero an int buffer (graph-capture-safe memset) ------------
__global__ void zero_k(int* __restrict__ p, int n) {
    int i = blockIdx.x * blockDim.x + threadIdx.x;
    if (i < n) p[i] = 0;
}

// ------ weight pre-swizzle: W1[128k x 512n] -> W1s[n][k] bf16 (k-contig) ----
__global__ void swz1_k(const float* __restrict__ W1, u16* __restrict__ W1s) {
    const int i = blockIdx.x * 256 + threadIdx.x;       // 65536
    const int k = i >> 9, n = i & 511;
    W1s[n * DIM + k] = f2bf(W1[i]);
}
// ------ W2[512k x 128n] -> W2s[n][k] bf16 (k-contig) ------------------------
__global__ void swz2_k(const float* __restrict__ W2, u16* __restrict__ W2s) {
    const int i = blockIdx.x * 256 + threadIdx.x;       // 65536
    const int k = i >> 7, n = i & 127;
    W2s[n * DFF + k] = f2bf(W2[i]);
}

// ---------------- LayerNorm 1 : h = LN(ent_feat)  (fp32 in/out) -------------
__global__ __launch_bounds__(128) void ln1_k(const float* __restrict__ x,
        const float* __restrict__ g, const float* __restrict__ b,
        float* __restrict__ h) {
    const int n = blockIdx.x, t = threadIdx.x;
    const float v = x[n * DIM + t];
    float s = v, q = v * v;
#pragma unroll
    for (int off = 32; off > 0; off >>= 1) {
        s += __shfl_xor(s, off, 64);
        q += __shfl_xor(q, off, 64);
    }
    __shared__ float ss[2], qq[2];
    if ((t & 63) == 0) { ss[t >> 6] = s; qq[t >> 6] = q; }
    __syncthreads();
    s = ss[0] + ss[1]; q = qq[0] + qq[1];
    const float mu  = s * (1.0f / 128.0f);
    const float var = q * (1.0f / 128.0f) - mu * mu;
    const float rs  = rsqrtf(fmaxf(var, 0.f) + LN_EPS);
    h[n * DIM + t] = (v - mu) * rs * g[t] + b[t];
}

// --------- feat0 = h @ W_ent (bf16 internal out) ; eh/et attn dots ----------
__global__ __launch_bounds__(256) void proj_k(const float* __restrict__ h,
        const float* __restrict__ W,
        const float* __restrict__ attn_h, const float* __restrict__ attn_t,
        u16* __restrict__ feat0, float* __restrict__ eh, float* __restrict__ et) {
    __shared__ float hs[8][DIM];
    const int t  = threadIdx.x;
    const int n0 = blockIdx.x * 8;
    {
        const int r = t >> 5;
        const int c = (t & 31) * 4;
        *(float4*)&hs[r][c] = *(const float4*)&h[(n0 + r) * DIM + c];
    }
    __syncthreads();
    const int node = t >> 5;
    const int j0   = (t & 31) * 4;
    float4 acc = {0.f, 0.f, 0.f, 0.f};
    for (int d = 0; d < DIM; d += 4) {
        const float4 h4 = *(const float4*)&hs[node][d];
        const float4 w0 = *(const float4*)&W[(d + 0) * DIM + j0];
        const float4 w1 = *(const float4*)&W[(d + 1) * DIM + j0];
        const float4 w2 = *(const float4*)&W[(d + 2) * DIM + j0];
        const float4 w3 = *(const float4*)&W[(d + 3) * DIM + j0];
        acc.x += h4.x * w0.x + h4.y * w1.x + h4.z * w2.x + h4.w * w3.x;
        acc.y += h4.x * w0.y + h4.y * w1.y + h4.z * w2.y + h4.w * w3.y;
        acc.z += h4.x * w0.z + h4.y * w1.z + h4.z * w2.z + h4.w * w3.z;
        acc.w += h4.x * w0.w + h4.y * w1.w + h4.z * w2.w + h4.w * w3.w;
    }
    const int n = n0 + node;
    ushort4 fo;
    fo.x = f2bf(acc.x); fo.y = f2bf(acc.y); fo.z = f2bf(acc.z); fo.w = f2bf(acc.w);
    *(ushort4*)&feat0[n * DIM + j0] = fo;
    const float4 ah = *(const float4*)&attn_h[j0];
    const float4 at = *(const float4*)&attn_t[j0];
    float ph = acc.x * ah.x + acc.y * ah.y + acc.z * ah.z + acc.w * ah.w;
    float pt = acc.x * at.x + acc.y * at.y + acc.z * at.z + acc.w * at.w;
    ph += __shfl_xor(ph, 1, 64); ph += __shfl_xor(ph, 2, 64);
    pt += __shfl_xor(pt, 1, 64); pt += __shfl_xor(pt, 2, 64);
    if ((t & 3) == 0) {
        const int head = (t & 31) >> 2;
        eh[n * NHEAD + head] = ph;
        et[n * NHEAD + head] = pt;
    }
}

// ---------------- er[r][head] = ((rel_feat @ W_rel) * attn_r).sum ----------
__global__ __launch_bounds__(128) void rel_k(const float* __restrict__ rel_feat,
        const float* __restrict__ W,
        const float* __restrict__ attn_r, float* __restrict__ er) {
    __shared__ float rf[DIM];
    __shared__ float pr[DIM];
    const int r = blockIdx.x, t = threadIdx.x;
    rf[t] = rel_feat[r * DIM + t];
    __syncthreads();
    float acc = 0.f;
    for (int d = 0; d < DIM; ++d) acc += rf[d] * W[d * DIM + t];
    pr[t] = acc * attn_r[t];
    __syncthreads();
    if (t < NHEAD) {
        float s = 0.f;
        for (int i = 0; i < 16; ++i) s += pr[t * 16 + i];
        er[r * NHEAD + t] = s;
    }
}

// ---------------- CSR build: histogram, scan, scatter ----------------------
__global__ void count_k(const int* __restrict__ dst, int* __restrict__ counts) {
    int e = blockIdx.x * blockDim.x + threadIdx.x;
    if (e < N_EDGES) atomicAdd(&counts[dst[e]], 1);
}

__global__ __launch_bounds__(64) void scan_k(const int* __restrict__ counts,
        int* __restrict__ offsets, int* __restrict__ cursor, int n) {
    const int lane = threadIdx.x;
    int base = 0;
    for (int start = 0; start < n; start += 512) {
        int v[8];
#pragma unroll
        for (int j = 0; j < 8; ++j) {
            const int i = start + j * 64 + lane;
            v[j] = (i < n) ? counts[i] : 0;
        }
#pragma unroll
        for (int j = 0; j < 8; ++j) {
            int incl = v[j];
#pragma unroll
            for (int off = 1; off < 64; off <<= 1) {
                const int tt = __shfl_up(incl, off, 64);
                if (lane >= off) incl += tt;
            }
            const int i = start + j * 64 + lane;
            const int excl = base + incl - v[j];
            if (i < n) { offsets[i] = excl; cursor[i] = excl; }
            base += __shfl(incl, 63, 64);
        }
    }
    if (lane == 0) offsets[n] = base;
}

__global__ void scatter_k(const int* __restrict__ src, const int* __restrict__ dst,
        const int* __restrict__ etype,
        const float* __restrict__ eh, const float* __restrict__ et,
        const float* __restrict__ er,
        int* __restrict__ cursor, int* __restrict__ csr_src,
        float* __restrict__ csr_a) {
    const int e = blockIdx.x * blockDim.x + threadIdx.x;
    if (e >= N_EDGES) return;
    const int s = src[e], d = dst[e], r = etype[e];
    const float4 h0 = *(const float4*)&eh[s * NHEAD];
    const float4 h1 = *(const float4*)&eh[s * NHEAD + 4];
    const float4 t0 = *(const float4*)&et[d * NHEAD];
    const float4 t1 = *(const float4*)&et[d * NHEAD + 4];
    const float4 r0 = *(const float4*)&er[r * NHEAD];
    const float4 r1 = *(const float4*)&er[r * NHEAD + 4];
    float4 a0, a1;
    a0.x = h0.x + t0.x + r0.x; a0.y = h0.y + t0.y + r0.y;
    a0.z = h0.z + t0.z + r0.z; a0.w = h0.w + t0.w + r0.w;
    a1.x = h1.x + t1.x + r1.x; a1.y = h1.y + t1.y + r1.y;
    a1.z = h1.z + t1.z + r1.z; a1.w = h1.w + t1.w + r1.w;
    a0.x = a0.x > 0.f ? a0.x : SLOPE * a0.x;
    a0.y = a0.y > 0.f ? a0.y : SLOPE * a0.y;
    a0.z = a0.z > 0.f ? a0.z : SLOPE * a0.z;
    a0.w = a0.w > 0.f ? a0.w : SLOPE * a0.w;
    a1.x = a1.x > 0.f ? a1.x : SLOPE * a1.x;
    a1.y = a1.y > 0.f ? a1.y : SLOPE * a1.y;
    a1.z = a1.z > 0.f ? a1.z : SLOPE * a1.z;
    a1.w = a1.w > 0.f ? a1.w : SLOPE * a1.w;
    const int pos = atomicAdd(&cursor[d], 1);
    if (pos < 0 || pos >= N_EDGES) return;   // defensive
    csr_src[pos] = s;
    *(float4*)&csr_a[pos * NHEAD]     = a0;
    *(float4*)&csr_a[pos * NHEAD + 4] = a1;
}

// --------- edge softmax over each node's incoming edges (in-place) ---------
__global__ __launch_bounds__(64) void softmax_k(const int* __restrict__ offsets,
        float* __restrict__ csr_a) {
    const int n = blockIdx.x;
    const int beg = offsets[n], end = offsets[n + 1];
    if (beg >= end) return;
    const int lane = threadIdx.x;
    const int k  = lane & 7;
    const int eo = lane >> 3;
    float m = -1e30f;
    for (int e = beg + eo; e < end; e += 8)
        m = fmaxf(m, csr_a[e * NHEAD + k]);
    m = fmaxf(m, __shfl_xor(m, 8, 64));
    m = fmaxf(m, __shfl_xor(m, 16, 64));
    m = fmaxf(m, __shfl_xor(m, 32, 64));
    float ssum = 0.f;
    for (int e = beg + eo; e < end; e += 8) {
        const float ex = expf(csr_a[e * NHEAD + k] - m);
        csr_a[e * NHEAD + k] = ex;
        ssum += ex;
    }
    ssum += __shfl_xor(ssum, 8, 64);
    ssum += __shfl_xor(ssum, 16, 64);
    ssum += __shfl_xor(ssum, 32, 64);
    const float inv = 1.f / fmaxf(ssum, 1e-20f);
    for (int e = beg + eo; e < end; e += 8)
        csr_a[e * NHEAD + k] *= inv;
}

// ---------------- one PPR diffusion hop (bf16 internal f buffers) ----------
// 4 nodes per 256-thread block (one wave each); 4-edge unroll for gather ILP.
__global__ __launch_bounds__(256) void hop_k(const u16* f_in,
        u16* __restrict__ f_out, const u16* feat0,
        const int* __restrict__ offsets, const int* __restrict__ csr_src,
        const float* __restrict__ csr_a) {
    const int n    = blockIdx.x * 4 + (threadIdx.x >> 6);
    const int lane = threadIdx.x & 63;
    const int beg = offsets[n], end = offsets[n + 1];
    const int hsel = lane >> 3;
    const int d2   = lane << 1;
    float2 acc = {0.f, 0.f};
    int e = beg;
    for (; e + 4 <= end; e += 4) {
        const int s0 = csr_src[e + 0];
        const int s1 = csr_src[e + 1];
        const int s2 = csr_src[e + 2];
        const int s3 = csr_src[e + 3];
        const float a0 = csr_a[(e + 0) * NHEAD + hsel];
        const float a1 = csr_a[(e + 1) * NHEAD + hsel];
        const float a2 = csr_a[(e + 2) * NHEAD + hsel];
        const float a3 = csr_a[(e + 3) * NHEAD + hsel];
        const ushort2 w0 = *(const ushort2*)&f_in[s0 * DIM + d2];
        const ushort2 w1 = *(const ushort2*)&f_in[s1 * DIM + d2];
        const ushort2 w2 = *(const ushort2*)&f_in[s2 * DIM + d2];
        const ushort2 w3 = *(const ushort2*)&f_in[s3 * DIM + d2];
        acc.x += a0 * bf2f(w0.x) + a1 * bf2f(w1.x) + a2 * bf2f(w2.x) + a3 * bf2f(w3.x);
        acc.y += a0 * bf2f(w0.y) + a1 * bf2f(w1.y) + a2 * bf2f(w2.y) + a3 * bf2f(w3.y);
    }
    for (; e < end; ++e) {
        const int s0 = csr_src[e];
        const float a0 = csr_a[e * NHEAD + hsel];
        const ushort2 w0 = *(const ushort2*)&f_in[s0 * DIM + d2];
        acc.x += a0 * bf2f(w0.x);
        acc.y += a0 * bf2f(w0.y);
    }
    const ushort2 p = *(const ushort2*)&feat0[n * DIM + d2];
    const float ox = (1.f - ALPHA) * acc.x + ALPHA * bf2f(p.x);
    const float oy = (1.f - ALPHA) * acc.y + ALPHA * bf2f(p.y);
    ushort2 o; o.x = f2bf(ox); o.y = f2bf(oy);
    *(ushort2*)&f_out[n * DIM + d2] = o;
}

// ---------------- FFN sublayer via MFMA bf16 + residuals, fp32 out ---------
// block = 256 threads (4 waves), 32 nodes/block.
// Fragment layouts (m89/m91-verified): A[m=lane&15][k=quad*8+j],
// B[k=quad*8+j][n=lane&15], D[row=quad*4+reg][col=lane&15].
#define YP 136   // ys row pitch (bf16), +8 pad: lane bank stride 4 -> 2-way (free)
#define ZP 520   // zs row pitch (bf16), +8 pad
__global__ __launch_bounds__(256) void ffn_k(const u16* __restrict__ f,
        const float* __restrict__ h,
        const float* __restrict__ g2, const float* __restrict__ b2ln,
        const u16* __restrict__ W1s,  // [DFF][DIM] bf16, k-contig
        const float* __restrict__ b1,
        const u16* __restrict__ W2s,  // [DIM][DFF] bf16, k-contig
        const float* __restrict__ b2,
        float* __restrict__ out) {
    __shared__ u16 ysb[32 * YP];
    __shared__ u16 zsb[32 * ZP];
    __shared__ float red[32][8];
    __shared__ float red2[32][8];
    __shared__ float mu_s[32], rs_s[32];

    const int t   = threadIdx.x;
    const int n0b = blockIdx.x * 32;

    // ---- Phase A: rst = f + h ; LN2 ; y -> ysb (bf16) ----
    const int an = t >> 3;       // node 0..31
    const int ap = t & 7;        // dim-slice 0..7 (16 dims each)
    float rv[16];
    {
        const int gbase = (n0b + an) * DIM + ap * 16;
#pragma unroll
        for (int i = 0; i < 4; ++i) {
            const ushort4 fu = *(const ushort4*)&f[gbase + i * 4];
            const float4  hv = *(const float4*)&h[gbase + i * 4];
            rv[i * 4 + 0] = bf2f(fu.x) + hv.x;
            rv[i * 4 + 1] = bf2f(fu.y) + hv.y;
            rv[i * 4 + 2] = bf2f(fu.z) + hv.z;
            rv[i * 4 + 3] = bf2f(fu.w) + hv.w;
        }
        float s = 0.f, q = 0.f;
#pragma unroll
        for (int i = 0; i < 16; ++i) { s += rv[i]; q += rv[i] * rv[i]; }
        red[an][ap] = s; red2[an][ap] = q;
    }
    __syncthreads();
    if (t < 32) {
        float s = 0.f, q = 0.f;
#pragma unroll
        for (int i = 0; i < 8; ++i) { s += red[t][i]; q += red2[t][i]; }
        const float mu  = s * (1.0f / 128.0f);
        const float var = q * (1.0f / 128.0f) - mu * mu;
        mu_s[t] = mu;
        rs_s[t] = rsqrtf(fmaxf(var, 0.f) + LN_EPS);
    }
    __syncthreads();
    {
        const float mu = mu_s[an], rs = rs_s[an];
#pragma unroll
        for (int i = 0; i < 4; ++i) {
            ushort4 yo;
            const int c = ap * 16 + i * 4;
            yo.x = f2bf((rv[i*4+0] - mu) * rs * g2[c+0] + b2ln[c+0]);
            yo.y = f2bf((rv[i*4+1] - mu) * rs * g2[c+1] + b2ln[c+1]);
            yo.z = f2bf((rv[i*4+2] - mu) * rs * g2[c+2] + b2ln[c+2]);
            yo.w = f2bf((rv[i*4+3] - mu) * rs * g2[c+3] + b2ln[c+3]);
            *(ushort4*)&ysb[an * YP + c] = yo;
        }
    }
    __syncthreads();

    const int wv   = t >> 6;     // wave 0..3
    const int lane = t & 63;
    const int lm   = lane & 15;  // m (A) or n (B/D col)
    const int q4   = lane >> 4;  // quad

    // ---- GEMM1: z = relu(y @ W1 + b1), wave wv owns cols [wv*128, +128) ----
    bf16x8 afr[2][4];
#pragma unroll
    for (int mt = 0; mt < 2; ++mt)
#pragma unroll
        for (int kt = 0; kt < 4; ++kt)
            afr[mt][kt] = *(const bf16x8*)&ysb[(mt * 16 + lm) * YP + kt * 32 + q4 * 8];

    for (int nt = 0; nt < 8; ++nt) {
        const int n0 = wv * 128 + nt * 16;
        f32x4 acc0 = {0.f, 0.f, 0.f, 0.f};
        f32x4 acc1 = {0.f, 0.f, 0.f, 0.f};
#pragma unroll
        for (int kt = 0; kt < 4; ++kt) {
            const bf16x8 bfr = *(const bf16x8*)&W1s[(n0 + lm) * DIM + kt * 32 + q4 * 8];
            acc0 = __builtin_amdgcn_mfma_f32_16x16x32_bf16(afr[0][kt], bfr, acc0, 0, 0, 0);
            acc1 = __builtin_amdgcn_mfma_f32_16x16x32_bf16(afr[1][kt], bfr, acc1, 0, 0, 0);
        }
        const float bias = b1[n0 + lm];
#pragma unroll
        for (int r = 0; r < 4; ++r) {
            zsb[(q4 * 4 + r) * ZP + n0 + lm]        = f2bf(fmaxf(acc0[r] + bias, 0.f));
            zsb[(16 + q4 * 4 + r) * ZP + n0 + lm]   = f2bf(fmaxf(acc1[r] + bias, 0.f));
        }
    }
    __syncthreads();

    // ---- GEMM2: ff = z @ W2 + b2, wave wv owns cols [wv*32, +32) ----
    f32x4 acc[2][2];
#pragma unroll
    for (int i = 0; i < 2; ++i)
#pragma unroll
        for (int j = 0; j < 2; ++j)
            acc[i][j] = (f32x4){0.f, 0.f, 0.f, 0.f};
    const int c0 = wv * 32;
    for (int kt = 0; kt < 16; ++kt) {
        const bf16x8 a0 = *(const bf16x8*)&zsb[(lm) * ZP + kt * 32 + q4 * 8];
        const bf16x8 a1 = *(const bf16x8*)&zsb[(16 + lm) * ZP + kt * 32 + q4 * 8];
        const bf16x8 b0 = *(const bf16x8*)&W2s[(c0 + lm) * DFF + kt * 32 + q4 * 8];
        const bf16x8 b1f = *(const bf16x8*)&W2s[(c0 + 16 + lm) * DFF + kt * 32 + q4 * 8];
        acc[0][0] = __builtin_amdgcn_mfma_f32_16x16x32_bf16(a0, b0, acc[0][0], 0, 0, 0);
        acc[0][1] = __builtin_amdgcn_mfma_f32_16x16x32_bf16(a0, b1f, acc[0][1], 0, 0, 0);
        acc[1][0] = __builtin_amdgcn_mfma_f32_16x16x32_bf16(a1, b0, acc[1][0], 0, 0, 0);
        acc[1][1] = __builtin_amdgcn_mfma_f32_16x16x32_bf16(a1, b1f, acc[1][1], 0, 0, 0);
    }

    // ---- epilogue: out = ff + b2 + (f + h) ----
#pragma unroll
    for (int ntile = 0; ntile < 2; ++ntile) {
        const int col = c0 + ntile * 16 + lm;
        const float bias = b2[col];
#pragma unroll
        for (int mt = 0; mt < 2; ++mt) {
#pragma unroll
            for (int r = 0; r < 4; ++r) {
                const int row  = mt * 16 + q4 * 4 + r;
                const int gidx = (n0b + row) * DIM + col;
                out[gidx] = acc[mt][ntile][r] + bias + bf2f(f[gidx]) + h[gidx];
            }
        }
    }
}

// ---------------------------------------------------------------------------
extern "C" void kernel_launch(void* const* d_in, const int* in_sizes, int n_in,
                              void* d_out, int out_size, void* d_ws, size_t ws_size,
                              hipStream_t stream) {
    const float* ent_feat = (const float*)d_in[0];
    const float* rel_feat = (const float*)d_in[1];
    const int*   src      = (const int*)d_in[2];
    const int*   dst      = (const int*)d_in[3];
    const int*   e_type   = (const int*)d_in[4];
    const float* ln1_g    = (const float*)d_in[5];
    const float* ln1_b    = (const float*)d_in[6];
    const float* W_ent    = (const float*)d_in[7];
    const float* W_rel    = (const float*)d_in[8];
    const float* attn_h   = (const float*)d_in[9];
    const float* attn_t   = (const float*)d_in[10];
    const float* attn_r   = (const float*)d_in[11];
    const float* ln2_g    = (const float*)d_in[12];
    const float* ln2_b    = (const float*)d_in[13];
    const float* W1       = (const float*)d_in[14];
    const float* b1       = (const float*)d_in[15];
    const float* W2       = (const float*)d_in[16];
    const float* b2       = (const float*)d_in[17];
    float* out = (float*)d_out;

    char* ws = (char*)d_ws;
    size_t used = 0;
    auto alloc = [&](size_t bytes) -> char* {
        char* p = ws + used;
        used += (bytes + 255) & ~(size_t)255;
        return p;
    };
    float* h       = (float*)alloc((size_t)N_NODES * DIM * 4);   // 51.2 MB
    u16*   feat0   = (u16*)  alloc((size_t)N_NODES * DIM * 2);   // 25.6 MB
    u16*   fA      = (u16*)  alloc((size_t)N_NODES * DIM * 2);   // 25.6 MB
    u16*   fB      = (u16*)  alloc((size_t)N_NODES * DIM * 2);   // 25.6 MB
    float* csr_a   = (float*)alloc((size_t)N_EDGES * NHEAD * 4); // 51.2 MB
    float* eh      = (float*)alloc((size_t)N_NODES * NHEAD * 4);
    float* et      = (float*)alloc((size_t)N_NODES * NHEAD * 4);
    int*   csr_src = (int*)  alloc((size_t)N_EDGES * 4);
    int*   counts  = (int*)  alloc((size_t)N_NODES * 4);
    int*   offsets = (int*)  alloc((size_t)(N_NODES + 1) * 4);
    int*   cursor  = (int*)  alloc((size_t)N_NODES * 4);
    float* er      = (float*)alloc((size_t)N_REL * NHEAD * 4);
    u16*   W1s     = (u16*)  alloc((size_t)DIM * DFF * 2);       // 128 KB
    u16*   W2s     = (u16*)  alloc((size_t)DFF * DIM * 2);       // 128 KB

    if (used > ws_size) return;   // diagnostic: absmax == max|ref|

    swz1_k<<<DIM * DFF / 256, 256, 0, stream>>>(W1, W1s);
    swz2_k<<<DFF * DIM / 256, 256, 0, stream>>>(W2, W2s);

    ln1_k<<<N_NODES, 128, 0, stream>>>(ent_feat, ln1_g, ln1_b, h);
    proj_k<<<N_NODES / 8, 256, 0, stream>>>(h, W_ent, attn_h, attn_t, feat0, eh, et);
    rel_k<<<N_REL, 128, 0, stream>>>(rel_feat, W_rel, attn_r, er);

    zero_k<<<(N_NODES + 255) / 256, 256, 0, stream>>>(counts, N_NODES);
    count_k<<<(N_EDGES + 255) / 256, 256, 0, stream>>>(dst, counts);
    scan_k<<<1, 64, 0, stream>>>(counts, offsets, cursor, N_NODES);
    scatter_k<<<(N_EDGES + 255) / 256, 256, 0, stream>>>(src, dst, e_type, eh, et, er,
                                                         cursor, csr_src, csr_a);
    softmax_k<<<N_NODES, 64, 0, stream>>>(offsets, csr_a);

    // 5 PPR hops: feat0 -> fA -> fB -> fA -> fB -> fA
    hop_k<<<N_NODES / 4, 256, 0, stream>>>(feat0, fA, feat0, offsets, csr_src, csr_a);
    hop_k<<<N_NODES / 4, 256, 0, stream>>>(fA, fB, feat0, offsets, csr_src, csr_a);
    hop_k<<<N_NODES / 4, 256, 0, stream>>>(fB, fA, feat0, offsets, csr_src, csr_a);
    hop_k<<<N_NODES / 4, 256, 0, stream>>>(fA, fB, feat0, offsets, csr_src, csr_a);
    hop_k<<<N_NODES / 4, 256, 0, stream>>>(fB, fA, feat0, offsets, csr_src, csr_a);

    // FFN + residuals (MFMA)
    ffn_k<<<N_NODES / 32, 256, 0, stream>>>(fA, h, ln2_g, ln2_b, W1s, b1, W2s, b2,
                                            out);
}

// Round 6
// 1131.058 us; speedup vs baseline: 2.0976x; 1.3504x over previous
//
#include <hip/hip_runtime.h>
#include <hip/hip_bf16.h>
#include <math.h>

#define N_NODES 100000
#define N_EDGES 1600000
#define N_REL   500
#define DIM     128
#define NHEAD   8
#define DFF     512
#define ALPHA   0.15f
#define SLOPE   0.2f
#define LN_EPS  1e-5f

#define SCHUNK   1024
#define NSCANBLK ((N_NODES + SCHUNK - 1) / SCHUNK)   // 98

typedef unsigned short u16;
typedef unsigned int   u32;

typedef __attribute__((ext_vector_type(8))) short  bf16x8;   // MFMA A/B frag
typedef __attribute__((ext_vector_type(4))) float  f32x4;    // MFMA C/D frag

__device__ __forceinline__ float bf2f(u16 u) {
    return __uint_as_float(((u32)u) << 16);
}
__device__ __forceinline__ u16 f2bf(float f) {
    __hip_bfloat16 b = __float2bfloat16(f);
    return *reinterpret_cast<u16*>(&b);
}

// ---------------- zero an int buffer (graph-capture-safe memset) ------------
__global__ void zero_k(int* __restrict__ p, int n) {
    int i = blockIdx.x * blockDim.x + threadIdx.x;
    if (i < n) p[i] = 0;
}

// ------ weight pre-swizzle: W1[128k x 512n] -> W1s[n][k] bf16 (k-contig) ----
__global__ void swz1_k(const float* __restrict__ W1, u16* __restrict__ W1s) {
    const int i = blockIdx.x * 256 + threadIdx.x;       // 65536
    const int k = i >> 9, n = i & 511;
    W1s[n * DIM + k] = f2bf(W1[i]);
}
// ------ W2[512k x 128n] -> W2s[n][k] bf16 (k-contig) ------------------------
__global__ void swz2_k(const float* __restrict__ W2, u16* __restrict__ W2s) {
    const int i = blockIdx.x * 256 + threadIdx.x;       // 65536
    const int k = i >> 7, n = i & 127;
    W2s[n * DFF + k] = f2bf(W2[i]);
}

// ---------------- LayerNorm 1 : h = LN(ent_feat)  (fp32 in/out) -------------
__global__ __launch_bounds__(128) void ln1_k(const float* __restrict__ x,
        const float* __restrict__ g, const float* __restrict__ b,
        float* __restrict__ h) {
    const int n = blockIdx.x, t = threadIdx.x;
    const float v = x[n * DIM + t];
    float s = v, q = v * v;
#pragma unroll
    for (int off = 32; off > 0; off >>= 1) {
        s += __shfl_xor(s, off, 64);
        q += __shfl_xor(q, off, 64);
    }
    __shared__ float ss[2], qq[2];
    if ((t & 63) == 0) { ss[t >> 6] = s; qq[t >> 6] = q; }
    __syncthreads();
    s = ss[0] + ss[1]; q = qq[0] + qq[1];
    const float mu  = s * (1.0f / 128.0f);
    const float var = q * (1.0f / 128.0f) - mu * mu;
    const float rs  = rsqrtf(fmaxf(var, 0.f) + LN_EPS);
    h[n * DIM + t] = (v - mu) * rs * g[t] + b[t];
}

// --------- feat0 = h @ W_ent (bf16 internal out) ; eh/et attn dots ----------
__global__ __launch_bounds__(256) void proj_k(const float* __restrict__ h,
        const float* __restrict__ W,
        const float* __restrict__ attn_h, const float* __restrict__ attn_t,
        u16* __restrict__ feat0, float* __restrict__ eh, float* __restrict__ et) {
    __shared__ float hs[8][DIM];
    const int t  = threadIdx.x;
    const int n0 = blockIdx.x * 8;
    {
        const int r = t >> 5;
        const int c = (t & 31) * 4;
        *(float4*)&hs[r][c] = *(const float4*)&h[(n0 + r) * DIM + c];
    }
    __syncthreads();
    const int node = t >> 5;
    const int j0   = (t & 31) * 4;
    float4 acc = {0.f, 0.f, 0.f, 0.f};
    for (int d = 0; d < DIM; d += 4) {
        const float4 h4 = *(const float4*)&hs[node][d];
        const float4 w0 = *(const float4*)&W[(d + 0) * DIM + j0];
        const float4 w1 = *(const float4*)&W[(d + 1) * DIM + j0];
        const float4 w2 = *(const float4*)&W[(d + 2) * DIM + j0];
        const float4 w3 = *(const float4*)&W[(d + 3) * DIM + j0];
        acc.x += h4.x * w0.x + h4.y * w1.x + h4.z * w2.x + h4.w * w3.x;
        acc.y += h4.x * w0.y + h4.y * w1.y + h4.z * w2.y + h4.w * w3.y;
        acc.z += h4.x * w0.z + h4.y * w1.z + h4.z * w2.z + h4.w * w3.z;
        acc.w += h4.x * w0.w + h4.y * w1.w + h4.z * w2.w + h4.w * w3.w;
    }
    const int n = n0 + node;
    ushort4 fo;
    fo.x = f2bf(acc.x); fo.y = f2bf(acc.y); fo.z = f2bf(acc.z); fo.w = f2bf(acc.w);
    *(ushort4*)&feat0[n * DIM + j0] = fo;
    const float4 ah = *(const float4*)&attn_h[j0];
    const float4 at = *(const float4*)&attn_t[j0];
    float ph = acc.x * ah.x + acc.y * ah.y + acc.z * ah.z + acc.w * ah.w;
    float pt = acc.x * at.x + acc.y * at.y + acc.z * at.z + acc.w * at.w;
    ph += __shfl_xor(ph, 1, 64); ph += __shfl_xor(ph, 2, 64);
    pt += __shfl_xor(pt, 1, 64); pt += __shfl_xor(pt, 2, 64);
    if ((t & 3) == 0) {
        const int head = (t & 31) >> 2;
        eh[n * NHEAD + head] = ph;
        et[n * NHEAD + head] = pt;
    }
}

// ---------------- er[r][head] = ((rel_feat @ W_rel) * attn_r).sum ----------
__global__ __launch_bounds__(128) void rel_k(const float* __restrict__ rel_feat,
        const float* __restrict__ W,
        const float* __restrict__ attn_r, float* __restrict__ er) {
    __shared__ float rf[DIM];
    __shared__ float pr[DIM];
    const int r = blockIdx.x, t = threadIdx.x;
    rf[t] = rel_feat[r * DIM + t];
    __syncthreads();
    float acc = 0.f;
    for (int d = 0; d < DIM; ++d) acc += rf[d] * W[d * DIM + t];
    pr[t] = acc * attn_r[t];
    __syncthreads();
    if (t < NHEAD) {
        float s = 0.f;
        for (int i = 0; i < 16; ++i) s += pr[t * 16 + i];
        er[r * NHEAD + t] = s;
    }
}

// ---------------- CSR build: histogram, 3-phase scan, scatter ---------------
__global__ void count_k(const int* __restrict__ dst, int* __restrict__ counts) {
    int e = blockIdx.x * blockDim.x + threadIdx.x;
    if (e < N_EDGES) atomicAdd(&counts[dst[e]], 1);
}

// phase 1: per-block (1024 elems) local exclusive scan + block sums
__global__ __launch_bounds__(256) void scan1_k(const int* __restrict__ counts,
        int* __restrict__ offsets, int* __restrict__ blk_sums, int n) {
    __shared__ int wsum[4];
    const int t = threadIdx.x, lane = t & 63, wid = t >> 6;
    const int base = blockIdx.x * SCHUNK + t * 4;
    int v0 = 0, v1 = 0, v2 = 0, v3 = 0;
    if (base + 3 < n) {
        const int4 c4 = *(const int4*)&counts[base];
        v0 = c4.x; v1 = c4.y; v2 = c4.z; v3 = c4.w;
    } else {
        if (base + 0 < n) v0 = counts[base + 0];
        if (base + 1 < n) v1 = counts[base + 1];
        if (base + 2 < n) v2 = counts[base + 2];
        if (base + 3 < n) v3 = counts[base + 3];
    }
    const int s4 = v0 + v1 + v2 + v3;
    int incl = s4;
#pragma unroll
    for (int off = 1; off < 64; off <<= 1) {
        const int tt = __shfl_up(incl, off, 64);
        if (lane >= off) incl += tt;
    }
    if (lane == 63) wsum[wid] = incl;
    __syncthreads();
    int wbase = 0;
#pragma unroll
    for (int w = 0; w < 4; ++w) if (w < wid) wbase += wsum[w];
    const int excl = wbase + incl - s4;
    if (base + 0 < n) offsets[base + 0] = excl;
    if (base + 1 < n) offsets[base + 1] = excl + v0;
    if (base + 2 < n) offsets[base + 2] = excl + v0 + v1;
    if (base + 3 < n) offsets[base + 3] = excl + v0 + v1 + v2;
    if (t == 255) blk_sums[blockIdx.x] = wbase + incl;
}

// phase 2: single block scans the 98 block sums (exclusive) + writes total
__global__ __launch_bounds__(128) void scan2_k(const int* __restrict__ blk_sums,
        int* __restrict__ blk_off, int* __restrict__ offsets, int nblk, int n) {
    const int t = threadIdx.x;
    const int v = (t < nblk) ? blk_sums[t] : 0;
    int incl = v;
#pragma unroll
    for (int off = 1; off < 64; off <<= 1) {
        const int tt = __shfl_up(incl, off, 64);
        if ((t & 63) >= off) incl += tt;
    }
    __shared__ int w0sum;
    if (t == 63) w0sum = incl;
    __syncthreads();
    int x = incl - v;
    if (t >= 64) x += w0sum;
    if (t < nblk) blk_off[t] = x;
    if (t == nblk - 1) offsets[n] = x + v;
}

// phase 3: add block offsets; fill cursor
__global__ __launch_bounds__(256) void scan3_k(int* __restrict__ offsets,
        int* __restrict__ cursor, const int* __restrict__ blk_off, int n) {
    const int add  = blk_off[blockIdx.x];
    const int base = blockIdx.x * SCHUNK + threadIdx.x * 4;
#pragma unroll
    for (int j = 0; j < 4; ++j) {
        const int i = base + j;
        if (i < n) {
            const int o = offsets[i] + add;
            offsets[i] = o;
            cursor[i]  = o;
        }
    }
}

__global__ void scatter_k(const int* __restrict__ src, const int* __restrict__ dst,
        const int* __restrict__ etype,
        const float* __restrict__ eh, const float* __restrict__ et,
        const float* __restrict__ er,
        int* __restrict__ cursor, int* __restrict__ csr_src,
        float* __restrict__ csr_a) {
    const int e = blockIdx.x * blockDim.x + threadIdx.x;
    if (e >= N_EDGES) return;
    const int s = src[e], d = dst[e], r = etype[e];
    const float4 h0 = *(const float4*)&eh[s * NHEAD];
    const float4 h1 = *(const float4*)&eh[s * NHEAD + 4];
    const float4 t0 = *(const float4*)&et[d * NHEAD];
    const float4 t1 = *(const float4*)&et[d * NHEAD + 4];
    const float4 r0 = *(const float4*)&er[r * NHEAD];
    const float4 r1 = *(const float4*)&er[r * NHEAD + 4];
    float4 a0, a1;
    a0.x = h0.x + t0.x + r0.x; a0.y = h0.y + t0.y + r0.y;
    a0.z = h0.z + t0.z + r0.z; a0.w = h0.w + t0.w + r0.w;
    a1.x = h1.x + t1.x + r1.x; a1.y = h1.y + t1.y + r1.y;
    a1.z = h1.z + t1.z + r1.z; a1.w = h1.w + t1.w + r1.w;
    a0.x = a0.x > 0.f ? a0.x : SLOPE * a0.x;
    a0.y = a0.y > 0.f ? a0.y : SLOPE * a0.y;
    a0.z = a0.z > 0.f ? a0.z : SLOPE * a0.z;
    a0.w = a0.w > 0.f ? a0.w : SLOPE * a0.w;
    a1.x = a1.x > 0.f ? a1.x : SLOPE * a1.x;
    a1.y = a1.y > 0.f ? a1.y : SLOPE * a1.y;
    a1.z = a1.z > 0.f ? a1.z : SLOPE * a1.z;
    a1.w = a1.w > 0.f ? a1.w : SLOPE * a1.w;
    const int pos = atomicAdd(&cursor[d], 1);
    if (pos < 0 || pos >= N_EDGES) return;   // defensive
    csr_src[pos] = s;
    *(float4*)&csr_a[pos * NHEAD]     = a0;
    *(float4*)&csr_a[pos * NHEAD + 4] = a1;
}

// --------- edge softmax, 4 nodes per 256-thread block (1 wave/node) --------
__global__ __launch_bounds__(256) void softmax_k(const int* __restrict__ offsets,
        float* __restrict__ csr_a) {
    const int n = blockIdx.x * 4 + (threadIdx.x >> 6);
    const int beg = offsets[n], end = offsets[n + 1];
    if (beg >= end) return;
    const int lane = threadIdx.x & 63;
    const int k  = lane & 7;
    const int eo = lane >> 3;
    float m = -1e30f;
    for (int e = beg + eo; e < end; e += 8)
        m = fmaxf(m, csr_a[e * NHEAD + k]);
    m = fmaxf(m, __shfl_xor(m, 8, 64));
    m = fmaxf(m, __shfl_xor(m, 16, 64));
    m = fmaxf(m, __shfl_xor(m, 32, 64));
    float ssum = 0.f;
    for (int e = beg + eo; e < end; e += 8) {
        const float ex = expf(csr_a[e * NHEAD + k] - m);
        csr_a[e * NHEAD + k] = ex;
        ssum += ex;
    }
    ssum += __shfl_xor(ssum, 8, 64);
    ssum += __shfl_xor(ssum, 16, 64);
    ssum += __shfl_xor(ssum, 32, 64);
    const float inv = 1.f / fmaxf(ssum, 1e-20f);
    for (int e = beg + eo; e < end; e += 8)
        csr_a[e * NHEAD + k] *= inv;
}

// ---------------- one PPR diffusion hop (bf16 internal f buffers) ----------
// 4 nodes per 256-thread block (one wave each); 4-edge unroll for gather ILP.
__global__ __launch_bounds__(256) void hop_k(const u16* f_in,
        u16* __restrict__ f_out, const u16* feat0,
        const int* __restrict__ offsets, const int* __restrict__ csr_src,
        const float* __restrict__ csr_a) {
    const int n    = blockIdx.x * 4 + (threadIdx.x >> 6);
    const int lane = threadIdx.x & 63;
    const int beg = offsets[n], end = offsets[n + 1];
    const int hsel = lane >> 3;
    const int d2   = lane << 1;
    float2 acc = {0.f, 0.f};
    int e = beg;
    for (; e + 4 <= end; e += 4) {
        const int s0 = csr_src[e + 0];
        const int s1 = csr_src[e + 1];
        const int s2 = csr_src[e + 2];
        const int s3 = csr_src[e + 3];
        const float a0 = csr_a[(e + 0) * NHEAD + hsel];
        const float a1 = csr_a[(e + 1) * NHEAD + hsel];
        const float a2 = csr_a[(e + 2) * NHEAD + hsel];
        const float a3 = csr_a[(e + 3) * NHEAD + hsel];
        const ushort2 w0 = *(const ushort2*)&f_in[s0 * DIM + d2];
        const ushort2 w1 = *(const ushort2*)&f_in[s1 * DIM + d2];
        const ushort2 w2 = *(const ushort2*)&f_in[s2 * DIM + d2];
        const ushort2 w3 = *(const ushort2*)&f_in[s3 * DIM + d2];
        acc.x += a0 * bf2f(w0.x) + a1 * bf2f(w1.x) + a2 * bf2f(w2.x) + a3 * bf2f(w3.x);
        acc.y += a0 * bf2f(w0.y) + a1 * bf2f(w1.y) + a2 * bf2f(w2.y) + a3 * bf2f(w3.y);
    }
    for (; e < end; ++e) {
        const int s0 = csr_src[e];
        const float a0 = csr_a[e * NHEAD + hsel];
        const ushort2 w0 = *(const ushort2*)&f_in[s0 * DIM + d2];
        acc.x += a0 * bf2f(w0.x);
        acc.y += a0 * bf2f(w0.y);
    }
    const ushort2 p = *(const ushort2*)&feat0[n * DIM + d2];
    const float ox = (1.f - ALPHA) * acc.x + ALPHA * bf2f(p.x);
    const float oy = (1.f - ALPHA) * acc.y + ALPHA * bf2f(p.y);
    ushort2 o; o.x = f2bf(ox); o.y = f2bf(oy);
    *(ushort2*)&f_out[n * DIM + d2] = o;
}

// ---------------- FFN sublayer via MFMA bf16 + residuals, fp32 out ---------
// block = 256 threads (4 waves), 32 nodes/block.
#define YP 136   // ys row pitch (bf16), +8 pad
#define ZP 520   // zs row pitch (bf16), +8 pad
__global__ __launch_bounds__(256) void ffn_k(const u16* __restrict__ f,
        const float* __restrict__ h,
        const float* __restrict__ g2, const float* __restrict__ b2ln,
        const u16* __restrict__ W1s,  // [DFF][DIM] bf16, k-contig
        const float* __restrict__ b1,
        const u16* __restrict__ W2s,  // [DIM][DFF] bf16, k-contig
        const float* __restrict__ b2,
        float* __restrict__ out) {
    __shared__ u16 ysb[32 * YP];
    __shared__ u16 zsb[32 * ZP];
    __shared__ float red[32][8];
    __shared__ float red2[32][8];
    __shared__ float mu_s[32], rs_s[32];

    const int t   = threadIdx.x;
    const int n0b = blockIdx.x * 32;

    // ---- Phase A: rst = f + h ; LN2 ; y -> ysb (bf16) ----
    const int an = t >> 3;       // node 0..31
    const int ap = t & 7;        // dim-slice 0..7 (16 dims each)
    float rv[16];
    {
        const int gbase = (n0b + an) * DIM + ap * 16;
#pragma unroll
        for (int i = 0; i < 4; ++i) {
            const ushort4 fu = *(const ushort4*)&f[gbase + i * 4];
            const float4  hv = *(const float4*)&h[gbase + i * 4];
            rv[i * 4 + 0] = bf2f(fu.x) + hv.x;
            rv[i * 4 + 1] = bf2f(fu.y) + hv.y;
            rv[i * 4 + 2] = bf2f(fu.z) + hv.z;
            rv[i * 4 + 3] = bf2f(fu.w) + hv.w;
        }
        float s = 0.f, q = 0.f;
#pragma unroll
        for (int i = 0; i < 16; ++i) { s += rv[i]; q += rv[i] * rv[i]; }
        red[an][ap] = s; red2[an][ap] = q;
    }
    __syncthreads();
    if (t < 32) {
        float s = 0.f, q = 0.f;
#pragma unroll
        for (int i = 0; i < 8; ++i) { s += red[t][i]; q += red2[t][i]; }
        const float mu  = s * (1.0f / 128.0f);
        const float var = q * (1.0f / 128.0f) - mu * mu;
        mu_s[t] = mu;
        rs_s[t] = rsqrtf(fmaxf(var, 0.f) + LN_EPS);
    }
    __syncthreads();
    {
        const float mu = mu_s[an], rs = rs_s[an];
#pragma unroll
        for (int i = 0; i < 4; ++i) {
            ushort4 yo;
            const int c = ap * 16 + i * 4;
            yo.x = f2bf((rv[i*4+0] - mu) * rs * g2[c+0] + b2ln[c+0]);
            yo.y = f2bf((rv[i*4+1] - mu) * rs * g2[c+1] + b2ln[c+1]);
            yo.z = f2bf((rv[i*4+2] - mu) * rs * g2[c+2] + b2ln[c+2]);
            yo.w = f2bf((rv[i*4+3] - mu) * rs * g2[c+3] + b2ln[c+3]);
            *(ushort4*)&ysb[an * YP + c] = yo;
        }
    }
    __syncthreads();

    const int wv   = t >> 6;     // wave 0..3
    const int lane = t & 63;
    const int lm   = lane & 15;  // m (A) or n (B/D col)
    const int q4   = lane >> 4;  // quad

    // ---- GEMM1: z = relu(y @ W1 + b1), wave wv owns cols [wv*128, +128) ----
    bf16x8 afr[2][4];
#pragma unroll
    for (int mt = 0; mt < 2; ++mt)
#pragma unroll
        for (int kt = 0; kt < 4; ++kt)
            afr[mt][kt] = *(const bf16x8*)&ysb[(mt * 16 + lm) * YP + kt * 32 + q4 * 8];

    for (int nt = 0; nt < 8; ++nt) {
        const int n0 = wv * 128 + nt * 16;
        f32x4 acc0 = {0.f, 0.f, 0.f, 0.f};
        f32x4 acc1 = {0.f, 0.f, 0.f, 0.f};
#pragma unroll
        for (int kt = 0; kt < 4; ++kt) {
            const bf16x8 bfr = *(const bf16x8*)&W1s[(n0 + lm) * DIM + kt * 32 + q4 * 8];
            acc0 = __builtin_amdgcn_mfma_f32_16x16x32_bf16(afr[0][kt], bfr, acc0, 0, 0, 0);
            acc1 = __builtin_amdgcn_mfma_f32_16x16x32_bf16(afr[1][kt], bfr, acc1, 0, 0, 0);
        }
        const float bias = b1[n0 + lm];
#pragma unroll
        for (int r = 0; r < 4; ++r) {
            zsb[(q4 * 4 + r) * ZP + n0 + lm]        = f2bf(fmaxf(acc0[r] + bias, 0.f));
            zsb[(16 + q4 * 4 + r) * ZP + n0 + lm]   = f2bf(fmaxf(acc1[r] + bias, 0.f));
        }
    }
    __syncthreads();

    // ---- GEMM2: ff = z @ W2 + b2, wave wv owns cols [wv*32, +32) ----
    f32x4 acc[2][2];
#pragma unroll
    for (int i = 0; i < 2; ++i)
#pragma unroll
        for (int j = 0; j < 2; ++j)
            acc[i][j] = (f32x4){0.f, 0.f, 0.f, 0.f};
    const int c0 = wv * 32;
    for (int kt = 0; kt < 16; ++kt) {
        const bf16x8 a0 = *(const bf16x8*)&zsb[(lm) * ZP + kt * 32 + q4 * 8];
        const bf16x8 a1 = *(const bf16x8*)&zsb[(16 + lm) * ZP + kt * 32 + q4 * 8];
        const bf16x8 b0 = *(const bf16x8*)&W2s[(c0 + lm) * DFF + kt * 32 + q4 * 8];
        const bf16x8 b1f = *(const bf16x8*)&W2s[(c0 + 16 + lm) * DFF + kt * 32 + q4 * 8];
        acc[0][0] = __builtin_amdgcn_mfma_f32_16x16x32_bf16(a0, b0, acc[0][0], 0, 0, 0);
        acc[0][1] = __builtin_amdgcn_mfma_f32_16x16x32_bf16(a0, b1f, acc[0][1], 0, 0, 0);
        acc[1][0] = __builtin_amdgcn_mfma_f32_16x16x32_bf16(a1, b0, acc[1][0], 0, 0, 0);
        acc[1][1] = __builtin_amdgcn_mfma_f32_16x16x32_bf16(a1, b1f, acc[1][1], 0, 0, 0);
    }

    // ---- epilogue: out = ff + b2 + (f + h) ----
#pragma unroll
    for (int ntile = 0; ntile < 2; ++ntile) {
        const int col = c0 + ntile * 16 + lm;
        const float bias = b2[col];
#pragma unroll
        for (int mt = 0; mt < 2; ++mt) {
#pragma unroll
            for (int r = 0; r < 4; ++r) {
                const int row  = mt * 16 + q4 * 4 + r;
                const int gidx = (n0b + row) * DIM + col;
                out[gidx] = acc[mt][ntile][r] + bias + bf2f(f[gidx]) + h[gidx];
            }
        }
    }
}

// ---------------------------------------------------------------------------
extern "C" void kernel_launch(void* const* d_in, const int* in_sizes, int n_in,
                              void* d_out, int out_size, void* d_ws, size_t ws_size,
                              hipStream_t stream) {
    const float* ent_feat = (const float*)d_in[0];
    const float* rel_feat = (const float*)d_in[1];
    const int*   src      = (const int*)d_in[2];
    const int*   dst      = (const int*)d_in[3];
    const int*   e_type   = (const int*)d_in[4];
    const float* ln1_g    = (const float*)d_in[5];
    const float* ln1_b    = (const float*)d_in[6];
    const float* W_ent    = (const float*)d_in[7];
    const float* W_rel    = (const float*)d_in[8];
    const float* attn_h   = (const float*)d_in[9];
    const float* attn_t   = (const float*)d_in[10];
    const float* attn_r   = (const float*)d_in[11];
    const float* ln2_g    = (const float*)d_in[12];
    const float* ln2_b    = (const float*)d_in[13];
    const float* W1       = (const float*)d_in[14];
    const float* b1       = (const float*)d_in[15];
    const float* W2       = (const float*)d_in[16];
    const float* b2       = (const float*)d_in[17];
    float* out = (float*)d_out;

    char* ws = (char*)d_ws;
    size_t used = 0;
    auto alloc = [&](size_t bytes) -> char* {
        char* p = ws + used;
        used += (bytes + 255) & ~(size_t)255;
        return p;
    };
    float* h       = (float*)alloc((size_t)N_NODES * DIM * 4);   // 51.2 MB
    u16*   feat0   = (u16*)  alloc((size_t)N_NODES * DIM * 2);   // 25.6 MB
    u16*   fA      = (u16*)  alloc((size_t)N_NODES * DIM * 2);   // 25.6 MB
    u16*   fB      = (u16*)  alloc((size_t)N_NODES * DIM * 2);   // 25.6 MB
    float* csr_a   = (float*)alloc((size_t)N_EDGES * NHEAD * 4); // 51.2 MB
    float* eh      = (float*)alloc((size_t)N_NODES * NHEAD * 4);
    float* et      = (float*)alloc((size_t)N_NODES * NHEAD * 4);
    int*   csr_src = (int*)  alloc((size_t)N_EDGES * 4);
    int*   counts  = (int*)  alloc((size_t)N_NODES * 4);
    int*   offsets = (int*)  alloc((size_t)(N_NODES + 1) * 4);
    int*   cursor  = (int*)  alloc((size_t)N_NODES * 4);
    float* er      = (float*)alloc((size_t)N_REL * NHEAD * 4);
    u16*   W1s     = (u16*)  alloc((size_t)DIM * DFF * 2);       // 128 KB
    u16*   W2s     = (u16*)  alloc((size_t)DFF * DIM * 2);       // 128 KB
    int*   blk_sums= (int*)  alloc((size_t)NSCANBLK * 4);
    int*   blk_off = (int*)  alloc((size_t)NSCANBLK * 4);

    if (used > ws_size) return;   // diagnostic: absmax == max|ref|

    swz1_k<<<DIM * DFF / 256, 256, 0, stream>>>(W1, W1s);
    swz2_k<<<DFF * DIM / 256, 256, 0, stream>>>(W2, W2s);

    ln1_k<<<N_NODES, 128, 0, stream>>>(ent_feat, ln1_g, ln1_b, h);
    proj_k<<<N_NODES / 8, 256, 0, stream>>>(h, W_ent, attn_h, attn_t, feat0, eh, et);
    rel_k<<<N_REL, 128, 0, stream>>>(rel_feat, W_rel, attn_r, er);

    zero_k<<<(N_NODES + 255) / 256, 256, 0, stream>>>(counts, N_NODES);
    count_k<<<(N_EDGES + 255) / 256, 256, 0, stream>>>(dst, counts);
    scan1_k<<<NSCANBLK, 256, 0, stream>>>(counts, offsets, blk_sums, N_NODES);
    scan2_k<<<1, 128, 0, stream>>>(blk_sums, blk_off, offsets, NSCANBLK, N_NODES);
    scan3_k<<<NSCANBLK, 256, 0, stream>>>(offsets, cursor, blk_off, N_NODES);
    scatter_k<<<(N_EDGES + 255) / 256, 256, 0, stream>>>(src, dst, e_type, eh, et, er,
                                                         cursor, csr_src, csr_a);
    softmax_k<<<N_NODES / 4, 256, 0, stream>>>(offsets, csr_a);

    // 5 PPR hops: feat0 -> fA -> fB -> fA -> fB -> fA
    hop_k<<<N_NODES / 4, 256, 0, stream>>>(feat0, fA, feat0, offsets, csr_src, csr_a);
    hop_k<<<N_NODES / 4, 256, 0, stream>>>(fA, fB, feat0, offsets, csr_src, csr_a);
    hop_k<<<N_NODES / 4, 256, 0, stream>>>(fB, fA, feat0, offsets, csr_src, csr_a);
    hop_k<<<N_NODES / 4, 256, 0, stream>>>(fA, fB, feat0, offsets, csr_src, csr_a);
    hop_k<<<N_NODES / 4, 256, 0, stream>>>(fB, fA, feat0, offsets, csr_src, csr_a);

    // FFN + residuals (MFMA)
    ffn_k<<<N_NODES / 32, 256, 0, stream>>>(fA, h, ln2_g, ln2_b, W1s, b1, W2s, b2,
                                            out);
}

// Round 7
// 954.673 us; speedup vs baseline: 2.4852x; 1.1848x over previous
//
#include <hip/hip_runtime.h>
#include <hip/hip_bf16.h>
#include <math.h>

#define N_NODES 100000
#define N_EDGES 1600000
#define N_REL   500
#define DIM     128
#define NHEAD   8
#define DFF     512
#define ALPHA   0.15f
#define SLOPE   0.2f
#define LN_EPS  1e-5f

#define SCHUNK   1024
#define NSCANBLK ((N_NODES + SCHUNK - 1) / SCHUNK)   // 98

typedef unsigned short u16;
typedef unsigned int   u32;

typedef __attribute__((ext_vector_type(8))) short  bf16x8;   // MFMA A/B frag
typedef __attribute__((ext_vector_type(4))) float  f32x4;    // MFMA C/D frag

__device__ __forceinline__ float bf2f(u16 u) {
    return __uint_as_float(((u32)u) << 16);
}
__device__ __forceinline__ u16 f2bf(float f) {
    __hip_bfloat16 b = __float2bfloat16(f);
    return *reinterpret_cast<u16*>(&b);
}
__device__ __forceinline__ u32 pack2(float a, float b) {
    return (u32)f2bf(a) | ((u32)f2bf(b) << 16);
}

// ---------------- zero an int buffer (graph-capture-safe memset) ------------
__global__ void zero_k(int* __restrict__ p, int n) {
    int i = blockIdx.x * blockDim.x + threadIdx.x;
    if (i < n) p[i] = 0;
}

// ------ weight pre-swizzles to bf16, k-contiguous [n][k] --------------------
__global__ void swz1_k(const float* __restrict__ W1, u16* __restrict__ W1s) {
    const int i = blockIdx.x * 256 + threadIdx.x;       // 65536
    const int k = i >> 9, n = i & 511;
    W1s[n * DIM + k] = f2bf(W1[i]);
}
__global__ void swz2_k(const float* __restrict__ W2, u16* __restrict__ W2s) {
    const int i = blockIdx.x * 256 + threadIdx.x;       // 65536
    const int k = i >> 7, n = i & 127;
    W2s[n * DFF + k] = f2bf(W2[i]);
}
__global__ void swze_k(const float* __restrict__ W, u16* __restrict__ Ws) {
    const int i = blockIdx.x * 256 + threadIdx.x;       // 16384
    const int k = i >> 7, n = i & 127;
    Ws[n * DIM + k] = f2bf(W[i]);
}

// ---------------- LayerNorm 1 : h = LN(ent_feat)  (fp32 in/out) -------------
__global__ __launch_bounds__(128) void ln1_k(const float* __restrict__ x,
        const float* __restrict__ g, const float* __restrict__ b,
        float* __restrict__ h) {
    const int n = blockIdx.x, t = threadIdx.x;
    const float v = x[n * DIM + t];
    float s = v, q = v * v;
#pragma unroll
    for (int off = 32; off > 0; off >>= 1) {
        s += __shfl_xor(s, off, 64);
        q += __shfl_xor(q, off, 64);
    }
    __shared__ float ss[2], qq[2];
    if ((t & 63) == 0) { ss[t >> 6] = s; qq[t >> 6] = q; }
    __syncthreads();
    s = ss[0] + ss[1]; q = qq[0] + qq[1];
    const float mu  = s * (1.0f / 128.0f);
    const float var = q * (1.0f / 128.0f) - mu * mu;
    const float rs  = rsqrtf(fmaxf(var, 0.f) + LN_EPS);
    h[n * DIM + t] = (v - mu) * rs * g[t] + b[t];
}

// --------- feat0 = h @ W_ent via MFMA bf16 (32 nodes/block, 4 waves) --------
#define HP 136   // hsb row pitch (u16), 136 = 8*17 (keeps 16B frag alignment)
__global__ __launch_bounds__(256) void proj_k(const float* __restrict__ h,
        const u16* __restrict__ Wes,  // [DIM n][DIM k] bf16, k-contig
        u16* __restrict__ feat0) {
    __shared__ u16 hsb[32 * HP];
    const int t   = threadIdx.x;
    const int n0b = blockIdx.x * 32;

    // stage h (fp32 -> bf16) into LDS: thread t -> row t>>3, 16 cols
    {
        const int sr = t >> 3;
        const int sc = (t & 7) * 16;
        const float* hrow = &h[(size_t)(n0b + sr) * DIM + sc];
        u16* drow = &hsb[sr * HP + sc];
#pragma unroll
        for (int i = 0; i < 4; ++i) {
            const float4 hv = ((const float4*)hrow)[i];
            ushort4 o;
            o.x = f2bf(hv.x); o.y = f2bf(hv.y); o.z = f2bf(hv.z); o.w = f2bf(hv.w);
            ((ushort4*)drow)[i] = o;
        }
    }
    __syncthreads();

    const int wv   = t >> 6;
    const int lane = t & 63;
    const int lm   = lane & 15;
    const int q4   = lane >> 4;
    const int mrow = (wv & 1) * 16;        // rows [mrow, mrow+16)
    const int chalf = (wv >> 1) * 64;      // cols [chalf, chalf+64)

    bf16x8 afr[4];
#pragma unroll
    for (int kt = 0; kt < 4; ++kt)
        afr[kt] = *(const bf16x8*)&hsb[(mrow + lm) * HP + kt * 32 + q4 * 8];

#pragma unroll
    for (int nt = 0; nt < 4; ++nt) {
        const int c0 = chalf + nt * 16;
        f32x4 acc = {0.f, 0.f, 0.f, 0.f};
#pragma unroll
        for (int kt = 0; kt < 4; ++kt) {
            const bf16x8 bfr = *(const bf16x8*)&Wes[(c0 + lm) * DIM + kt * 32 + q4 * 8];
            acc = __builtin_amdgcn_mfma_f32_16x16x32_bf16(afr[kt], bfr, acc, 0, 0, 0);
        }
#pragma unroll
        for (int r = 0; r < 4; ++r)
            feat0[(size_t)(n0b + mrow + q4 * 4 + r) * DIM + c0 + lm] = f2bf(acc[r]);
    }
}

// --------- eh/et: per-head attn dots from feat0 -----------------------------
__global__ __launch_bounds__(256) void eh_k(const u16* __restrict__ feat0,
        const float* __restrict__ attn_h, const float* __restrict__ attn_t,
        float* __restrict__ eh, float* __restrict__ et) {
    __shared__ float ahs[DIM], ats[DIM];
    const int t = threadIdx.x;
    if (t < DIM) { ahs[t] = attn_h[t]; ats[t] = attn_t[t]; }
    __syncthreads();
    const int idx  = blockIdx.x * 256 + t;
    const int n    = idx >> 3;
    const int head = idx & 7;
    const u16* fp = &feat0[(size_t)n * DIM + head * 16];
    float sh = 0.f, st = 0.f;
#pragma unroll
    for (int i = 0; i < 4; ++i) {
        const ushort4 f4 = ((const ushort4*)fp)[i];
        const int c = head * 16 + i * 4;
        sh += bf2f(f4.x) * ahs[c+0] + bf2f(f4.y) * ahs[c+1]
            + bf2f(f4.z) * ahs[c+2] + bf2f(f4.w) * ahs[c+3];
        st += bf2f(f4.x) * ats[c+0] + bf2f(f4.y) * ats[c+1]
            + bf2f(f4.z) * ats[c+2] + bf2f(f4.w) * ats[c+3];
    }
    eh[idx] = sh;
    et[idx] = st;
}

// ---------------- er[r][head] = ((rel_feat @ W_rel) * attn_r).sum ----------
__global__ __launch_bounds__(128) void rel_k(const float* __restrict__ rel_feat,
        const float* __restrict__ W,
        const float* __restrict__ attn_r, float* __restrict__ er) {
    __shared__ float rf[DIM];
    __shared__ float pr[DIM];
    const int r = blockIdx.x, t = threadIdx.x;
    rf[t] = rel_feat[r * DIM + t];
    __syncthreads();
    float acc = 0.f;
    for (int d = 0; d < DIM; ++d) acc += rf[d] * W[d * DIM + t];
    pr[t] = acc * attn_r[t];
    __syncthreads();
    if (t < NHEAD) {
        float s = 0.f;
        for (int i = 0; i < 16; ++i) s += pr[t * 16 + i];
        er[r * NHEAD + t] = s;
    }
}

// ---------------- CSR build: histogram, 3-phase scan, scatter ---------------
__global__ void count_k(const int* __restrict__ dst, int* __restrict__ counts) {
    int e = blockIdx.x * blockDim.x + threadIdx.x;
    if (e < N_EDGES) atomicAdd(&counts[dst[e]], 1);
}

__global__ __launch_bounds__(256) void scan1_k(const int* __restrict__ counts,
        int* __restrict__ offsets, int* __restrict__ blk_sums, int n) {
    __shared__ int wsum[4];
    const int t = threadIdx.x, lane = t & 63, wid = t >> 6;
    const int base = blockIdx.x * SCHUNK + t * 4;
    int v0 = 0, v1 = 0, v2 = 0, v3 = 0;
    if (base + 3 < n) {
        const int4 c4 = *(const int4*)&counts[base];
        v0 = c4.x; v1 = c4.y; v2 = c4.z; v3 = c4.w;
    } else {
        if (base + 0 < n) v0 = counts[base + 0];
        if (base + 1 < n) v1 = counts[base + 1];
        if (base + 2 < n) v2 = counts[base + 2];
        if (base + 3 < n) v3 = counts[base + 3];
    }
    const int s4 = v0 + v1 + v2 + v3;
    int incl = s4;
#pragma unroll
    for (int off = 1; off < 64; off <<= 1) {
        const int tt = __shfl_up(incl, off, 64);
        if (lane >= off) incl += tt;
    }
    if (lane == 63) wsum[wid] = incl;
    __syncthreads();
    int wbase = 0;
#pragma unroll
    for (int w = 0; w < 4; ++w) if (w < wid) wbase += wsum[w];
    const int excl = wbase + incl - s4;
    if (base + 0 < n) offsets[base + 0] = excl;
    if (base + 1 < n) offsets[base + 1] = excl + v0;
    if (base + 2 < n) offsets[base + 2] = excl + v0 + v1;
    if (base + 3 < n) offsets[base + 3] = excl + v0 + v1 + v2;
    if (t == 255) blk_sums[blockIdx.x] = wbase + incl;
}

__global__ __launch_bounds__(128) void scan2_k(const int* __restrict__ blk_sums,
        int* __restrict__ blk_off, int* __restrict__ offsets, int nblk, int n) {
    const int t = threadIdx.x;
    const int v = (t < nblk) ? blk_sums[t] : 0;
    int incl = v;
#pragma unroll
    for (int off = 1; off < 64; off <<= 1) {
        const int tt = __shfl_up(incl, off, 64);
        if ((t & 63) >= off) incl += tt;
    }
    __shared__ int w0sum;
    if (t == 63) w0sum = incl;
    __syncthreads();
    int x = incl - v;
    if (t >= 64) x += w0sum;
    if (t < nblk) blk_off[t] = x;
    if (t == nblk - 1) offsets[n] = x + v;
}

__global__ __launch_bounds__(256) void scan3_k(int* __restrict__ offsets,
        int* __restrict__ cursor, const int* __restrict__ blk_off, int n) {
    const int add  = blk_off[blockIdx.x];
    const int base = blockIdx.x * SCHUNK + threadIdx.x * 4;
#pragma unroll
    for (int j = 0; j < 4; ++j) {
        const int i = base + j;
        if (i < n) {
            const int o = offsets[i] + add;
            offsets[i] = o;
            cursor[i]  = o;
        }
    }
}

// scatter: edge scores (leaky-relu'd) stored bf16 into csr_ab[E][8]
__global__ void scatter_k(const int* __restrict__ src, const int* __restrict__ dst,
        const int* __restrict__ etype,
        const float* __restrict__ eh, const float* __restrict__ et,
        const float* __restrict__ er,
        int* __restrict__ cursor, int* __restrict__ csr_src,
        u16* __restrict__ csr_ab) {
    const int e = blockIdx.x * blockDim.x + threadIdx.x;
    if (e >= N_EDGES) return;
    const int s = src[e], d = dst[e], r = etype[e];
    const float4 h0 = *(const float4*)&eh[s * NHEAD];
    const float4 h1 = *(const float4*)&eh[s * NHEAD + 4];
    const float4 t0 = *(const float4*)&et[d * NHEAD];
    const float4 t1 = *(const float4*)&et[d * NHEAD + 4];
    const float4 r0 = *(const float4*)&er[r * NHEAD];
    const float4 r1 = *(const float4*)&er[r * NHEAD + 4];
    float4 a0, a1;
    a0.x = h0.x + t0.x + r0.x; a0.y = h0.y + t0.y + r0.y;
    a0.z = h0.z + t0.z + r0.z; a0.w = h0.w + t0.w + r0.w;
    a1.x = h1.x + t1.x + r1.x; a1.y = h1.y + t1.y + r1.y;
    a1.z = h1.z + t1.z + r1.z; a1.w = h1.w + t1.w + r1.w;
    a0.x = a0.x > 0.f ? a0.x : SLOPE * a0.x;
    a0.y = a0.y > 0.f ? a0.y : SLOPE * a0.y;
    a0.z = a0.z > 0.f ? a0.z : SLOPE * a0.z;
    a0.w = a0.w > 0.f ? a0.w : SLOPE * a0.w;
    a1.x = a1.x > 0.f ? a1.x : SLOPE * a1.x;
    a1.y = a1.y > 0.f ? a1.y : SLOPE * a1.y;
    a1.z = a1.z > 0.f ? a1.z : SLOPE * a1.z;
    a1.w = a1.w > 0.f ? a1.w : SLOPE * a1.w;
    const int pos = atomicAdd(&cursor[d], 1);
    if (pos < 0 || pos >= N_EDGES) return;   // defensive
    csr_src[pos] = s;
    uint4 packed;
    packed.x = pack2(a0.x, a0.y);
    packed.y = pack2(a0.z, a0.w);
    packed.z = pack2(a1.x, a1.y);
    packed.w = pack2(a1.z, a1.w);
    *(uint4*)&csr_ab[(size_t)pos * NHEAD] = packed;
}

// --------- edge softmax: in-place exp (bf16), inv_ssum to side buffer -------
// 4 nodes per 256-thread block (1 wave/node); lane -> (slot=lane/8, head=lane%8)
__global__ __launch_bounds__(256) void softmax_k(const int* __restrict__ offsets,
        u16* __restrict__ csr_ab, float* __restrict__ inv_buf) {
    const int n = blockIdx.x * 4 + (threadIdx.x >> 6);
    const int beg = offsets[n], end = offsets[n + 1];
    const int lane = threadIdx.x & 63;
    const int k  = lane & 7;
    const int eo = lane >> 3;
    float m = -1e30f;
    for (int e = beg + eo; e < end; e += 8)
        m = fmaxf(m, bf2f(csr_ab[(size_t)e * NHEAD + k]));
    m = fmaxf(m, __shfl_xor(m, 8, 64));
    m = fmaxf(m, __shfl_xor(m, 16, 64));
    m = fmaxf(m, __shfl_xor(m, 32, 64));
    float ssum = 0.f;
    for (int e = beg + eo; e < end; e += 8) {
        const float ex = expf(bf2f(csr_ab[(size_t)e * NHEAD + k]) - m);
        csr_ab[(size_t)e * NHEAD + k] = f2bf(ex);
        ssum += ex;
    }
    ssum += __shfl_xor(ssum, 8, 64);
    ssum += __shfl_xor(ssum, 16, 64);
    ssum += __shfl_xor(ssum, 32, 64);
    const float inv = 1.f / fmaxf(ssum, 1e-20f);
    if (lane < 8) inv_buf[n * NHEAD + lane] = inv;
}

// ---------------- one PPR diffusion hop (bf16 f, bf16 a, deferred norm) ----
__global__ __launch_bounds__(256) void hop_k(const u16* f_in,
        u16* __restrict__ f_out, const u16* feat0,
        const int* __restrict__ offsets, const int* __restrict__ csr_src,
        const u16* __restrict__ csr_ab, const float* __restrict__ inv_buf) {
    const int n    = blockIdx.x * 4 + (threadIdx.x >> 6);
    const int lane = threadIdx.x & 63;
    const int beg = offsets[n], end = offsets[n + 1];
    const int hsel = lane >> 3;
    const int d2   = lane << 1;
    float2 acc = {0.f, 0.f};
    int e = beg;
    for (; e + 4 <= end; e += 4) {
        const int s0 = csr_src[e + 0];
        const int s1 = csr_src[e + 1];
        const int s2 = csr_src[e + 2];
        const int s3 = csr_src[e + 3];
        const float a0 = bf2f(csr_ab[(size_t)(e + 0) * NHEAD + hsel]);
        const float a1 = bf2f(csr_ab[(size_t)(e + 1) * NHEAD + hsel]);
        const float a2 = bf2f(csr_ab[(size_t)(e + 2) * NHEAD + hsel]);
        const float a3 = bf2f(csr_ab[(size_t)(e + 3) * NHEAD + hsel]);
        const ushort2 w0 = *(const ushort2*)&f_in[s0 * DIM + d2];
        const ushort2 w1 = *(const ushort2*)&f_in[s1 * DIM + d2];
        const ushort2 w2 = *(const ushort2*)&f_in[s2 * DIM + d2];
        const ushort2 w3 = *(const ushort2*)&f_in[s3 * DIM + d2];
        acc.x += a0 * bf2f(w0.x) + a1 * bf2f(w1.x) + a2 * bf2f(w2.x) + a3 * bf2f(w3.x);
        acc.y += a0 * bf2f(w0.y) + a1 * bf2f(w1.y) + a2 * bf2f(w2.y) + a3 * bf2f(w3.y);
    }
    for (; e < end; ++e) {
        const int s0 = csr_src[e];
        const float a0 = bf2f(csr_ab[(size_t)e * NHEAD + hsel]);
        const ushort2 w0 = *(const ushort2*)&f_in[s0 * DIM + d2];
        acc.x += a0 * bf2f(w0.x);
        acc.y += a0 * bf2f(w0.y);
    }
    const float iv = inv_buf[n * NHEAD + hsel];
    const ushort2 p = *(const ushort2*)&feat0[n * DIM + d2];
    const float ox = (1.f - ALPHA) * acc.x * iv + ALPHA * bf2f(p.x);
    const float oy = (1.f - ALPHA) * acc.y * iv + ALPHA * bf2f(p.y);
    ushort2 o; o.x = f2bf(ox); o.y = f2bf(oy);
    *(ushort2*)&f_out[n * DIM + d2] = o;
}

// ---------------- FFN sublayer via MFMA bf16 + residuals, fp32 out ---------
#define YP 136
#define ZP 520
__global__ __launch_bounds__(256) void ffn_k(const u16* __restrict__ f,
        const float* __restrict__ h,
        const float* __restrict__ g2, const float* __restrict__ b2ln,
        const u16* __restrict__ W1s,  // [DFF][DIM] bf16, k-contig
        const float* __restrict__ b1,
        const u16* __restrict__ W2s,  // [DIM][DFF] bf16, k-contig
        const float* __restrict__ b2,
        float* __restrict__ out) {
    __shared__ u16 ysb[32 * YP];
    __shared__ u16 zsb[32 * ZP];
    __shared__ float red[32][8];
    __shared__ float red2[32][8];
    __shared__ float mu_s[32], rs_s[32];

    const int t   = threadIdx.x;
    const int n0b = blockIdx.x * 32;

    const int an = t >> 3;
    const int ap = t & 7;
    float rv[16];
    {
        const int gbase = (n0b + an) * DIM + ap * 16;
#pragma unroll
        for (int i = 0; i < 4; ++i) {
            const ushort4 fu = *(const ushort4*)&f[gbase + i * 4];
            const float4  hv = *(const float4*)&h[gbase + i * 4];
            rv[i * 4 + 0] = bf2f(fu.x) + hv.x;
            rv[i * 4 + 1] = bf2f(fu.y) + hv.y;
            rv[i * 4 + 2] = bf2f(fu.z) + hv.z;
            rv[i * 4 + 3] = bf2f(fu.w) + hv.w;
        }
        float s = 0.f, q = 0.f;
#pragma unroll
        for (int i = 0; i < 16; ++i) { s += rv[i]; q += rv[i] * rv[i]; }
        red[an][ap] = s; red2[an][ap] = q;
    }
    __syncthreads();
    if (t < 32) {
        float s = 0.f, q = 0.f;
#pragma unroll
        for (int i = 0; i < 8; ++i) { s += red[t][i]; q += red2[t][i]; }
        const float mu  = s * (1.0f / 128.0f);
        const float var = q * (1.0f / 128.0f) - mu * mu;
        mu_s[t] = mu;
        rs_s[t] = rsqrtf(fmaxf(var, 0.f) + LN_EPS);
    }
    __syncthreads();
    {
        const float mu = mu_s[an], rs = rs_s[an];
#pragma unroll
        for (int i = 0; i < 4; ++i) {
            ushort4 yo;
            const int c = ap * 16 + i * 4;
            yo.x = f2bf((rv[i*4+0] - mu) * rs * g2[c+0] + b2ln[c+0]);
            yo.y = f2bf((rv[i*4+1] - mu) * rs * g2[c+1] + b2ln[c+1]);
            yo.z = f2bf((rv[i*4+2] - mu) * rs * g2[c+2] + b2ln[c+2]);
            yo.w = f2bf((rv[i*4+3] - mu) * rs * g2[c+3] + b2ln[c+3]);
            *(ushort4*)&ysb[an * YP + c] = yo;
        }
    }
    __syncthreads();

    const int wv   = t >> 6;
    const int lane = t & 63;
    const int lm   = lane & 15;
    const int q4   = lane >> 4;

    bf16x8 afr[2][4];
#pragma unroll
    for (int mt = 0; mt < 2; ++mt)
#pragma unroll
        for (int kt = 0; kt < 4; ++kt)
            afr[mt][kt] = *(const bf16x8*)&ysb[(mt * 16 + lm) * YP + kt * 32 + q4 * 8];

    for (int nt = 0; nt < 8; ++nt) {
        const int n0 = wv * 128 + nt * 16;
        f32x4 acc0 = {0.f, 0.f, 0.f, 0.f};
        f32x4 acc1 = {0.f, 0.f, 0.f, 0.f};
#pragma unroll
        for (int kt = 0; kt < 4; ++kt) {
            const bf16x8 bfr = *(const bf16x8*)&W1s[(n0 + lm) * DIM + kt * 32 + q4 * 8];
            acc0 = __builtin_amdgcn_mfma_f32_16x16x32_bf16(afr[0][kt], bfr, acc0, 0, 0, 0);
            acc1 = __builtin_amdgcn_mfma_f32_16x16x32_bf16(afr[1][kt], bfr, acc1, 0, 0, 0);
        }
        const float bias = b1[n0 + lm];
#pragma unroll
        for (int r = 0; r < 4; ++r) {
            zsb[(q4 * 4 + r) * ZP + n0 + lm]        = f2bf(fmaxf(acc0[r] + bias, 0.f));
            zsb[(16 + q4 * 4 + r) * ZP + n0 + lm]   = f2bf(fmaxf(acc1[r] + bias, 0.f));
        }
    }
    __syncthreads();

    f32x4 acc[2][2];
#pragma unroll
    for (int i = 0; i < 2; ++i)
#pragma unroll
        for (int j = 0; j < 2; ++j)
            acc[i][j] = (f32x4){0.f, 0.f, 0.f, 0.f};
    const int c0 = wv * 32;
    for (int kt = 0; kt < 16; ++kt) {
        const bf16x8 a0 = *(const bf16x8*)&zsb[(lm) * ZP + kt * 32 + q4 * 8];
        const bf16x8 a1 = *(const bf16x8*)&zsb[(16 + lm) * ZP + kt * 32 + q4 * 8];
        const bf16x8 b0 = *(const bf16x8*)&W2s[(c0 + lm) * DFF + kt * 32 + q4 * 8];
        const bf16x8 b1f = *(const bf16x8*)&W2s[(c0 + 16 + lm) * DFF + kt * 32 + q4 * 8];
        acc[0][0] = __builtin_amdgcn_mfma_f32_16x16x32_bf16(a0, b0, acc[0][0], 0, 0, 0);
        acc[0][1] = __builtin_amdgcn_mfma_f32_16x16x32_bf16(a0, b1f, acc[0][1], 0, 0, 0);
        acc[1][0] = __builtin_amdgcn_mfma_f32_16x16x32_bf16(a1, b0, acc[1][0], 0, 0, 0);
        acc[1][1] = __builtin_amdgcn_mfma_f32_16x16x32_bf16(a1, b1f, acc[1][1], 0, 0, 0);
    }

#pragma unroll
    for (int ntile = 0; ntile < 2; ++ntile) {
        const int col = c0 + ntile * 16 + lm;
        const float bias = b2[col];
#pragma unroll
        for (int mt = 0; mt < 2; ++mt) {
#pragma unroll
            for (int r = 0; r < 4; ++r) {
                const int row  = mt * 16 + q4 * 4 + r;
                const int gidx = (n0b + row) * DIM + col;
                out[gidx] = acc[mt][ntile][r] + bias + bf2f(f[gidx]) + h[gidx];
            }
        }
    }
}

// ---------------------------------------------------------------------------
extern "C" void kernel_launch(void* const* d_in, const int* in_sizes, int n_in,
                              void* d_out, int out_size, void* d_ws, size_t ws_size,
                              hipStream_t stream) {
    const float* ent_feat = (const float*)d_in[0];
    const float* rel_feat = (const float*)d_in[1];
    const int*   src      = (const int*)d_in[2];
    const int*   dst      = (const int*)d_in[3];
    const int*   e_type   = (const int*)d_in[4];
    const float* ln1_g    = (const float*)d_in[5];
    const float* ln1_b    = (const float*)d_in[6];
    const float* W_ent    = (const float*)d_in[7];
    const float* W_rel    = (const float*)d_in[8];
    const float* attn_h   = (const float*)d_in[9];
    const float* attn_t   = (const float*)d_in[10];
    const float* attn_r   = (const float*)d_in[11];
    const float* ln2_g    = (const float*)d_in[12];
    const float* ln2_b    = (const float*)d_in[13];
    const float* W1       = (const float*)d_in[14];
    const float* b1       = (const float*)d_in[15];
    const float* W2       = (const float*)d_in[16];
    const float* b2       = (const float*)d_in[17];
    float* out = (float*)d_out;

    char* ws = (char*)d_ws;
    size_t used = 0;
    auto alloc = [&](size_t bytes) -> char* {
        char* p = ws + used;
        used += (bytes + 255) & ~(size_t)255;
        return p;
    };
    float* h       = (float*)alloc((size_t)N_NODES * DIM * 4);   // 51.2 MB
    u16*   feat0   = (u16*)  alloc((size_t)N_NODES * DIM * 2);   // 25.6 MB
    u16*   fA      = (u16*)  alloc((size_t)N_NODES * DIM * 2);   // 25.6 MB
    u16*   fB      = (u16*)  alloc((size_t)N_NODES * DIM * 2);   // 25.6 MB
    u16*   csr_ab  = (u16*)  alloc((size_t)N_EDGES * NHEAD * 2); // 25.6 MB
    float* eh      = (float*)alloc((size_t)N_NODES * NHEAD * 4); // 3.2 MB
    float* et      = (float*)alloc((size_t)N_NODES * NHEAD * 4); // 3.2 MB
    float* inv_buf = (float*)alloc((size_t)N_NODES * NHEAD * 4); // 3.2 MB
    int*   csr_src = (int*)  alloc((size_t)N_EDGES * 4);         // 6.4 MB
    int*   counts  = (int*)  alloc((size_t)N_NODES * 4);
    int*   offsets = (int*)  alloc((size_t)(N_NODES + 1) * 4);
    int*   cursor  = (int*)  alloc((size_t)N_NODES * 4);
    float* er      = (float*)alloc((size_t)N_REL * NHEAD * 4);
    u16*   W1s     = (u16*)  alloc((size_t)DIM * DFF * 2);
    u16*   W2s     = (u16*)  alloc((size_t)DFF * DIM * 2);
    u16*   Wes     = (u16*)  alloc((size_t)DIM * DIM * 2);
    int*   blk_sums= (int*)  alloc((size_t)NSCANBLK * 4);
    int*   blk_off = (int*)  alloc((size_t)NSCANBLK * 4);

    if (used > ws_size) return;   // diagnostic: absmax == max|ref|

    swz1_k<<<DIM * DFF / 256, 256, 0, stream>>>(W1, W1s);
    swz2_k<<<DFF * DIM / 256, 256, 0, stream>>>(W2, W2s);
    swze_k<<<DIM * DIM / 256, 256, 0, stream>>>(W_ent, Wes);

    ln1_k<<<N_NODES, 128, 0, stream>>>(ent_feat, ln1_g, ln1_b, h);
    proj_k<<<N_NODES / 32, 256, 0, stream>>>(h, Wes, feat0);
    eh_k<<<N_NODES * NHEAD / 256, 256, 0, stream>>>(feat0, attn_h, attn_t, eh, et);
    rel_k<<<N_REL, 128, 0, stream>>>(rel_feat, W_rel, attn_r, er);

    zero_k<<<(N_NODES + 255) / 256, 256, 0, stream>>>(counts, N_NODES);
    count_k<<<(N_EDGES + 255) / 256, 256, 0, stream>>>(dst, counts);
    scan1_k<<<NSCANBLK, 256, 0, stream>>>(counts, offsets, blk_sums, N_NODES);
    scan2_k<<<1, 128, 0, stream>>>(blk_sums, blk_off, offsets, NSCANBLK, N_NODES);
    scan3_k<<<NSCANBLK, 256, 0, stream>>>(offsets, cursor, blk_off, N_NODES);
    scatter_k<<<(N_EDGES + 255) / 256, 256, 0, stream>>>(src, dst, e_type, eh, et, er,
                                                         cursor, csr_src, csr_ab);
    softmax_k<<<N_NODES / 4, 256, 0, stream>>>(offsets, csr_ab, inv_buf);

    // 5 PPR hops: feat0 -> fA -> fB -> fA -> fB -> fA
    hop_k<<<N_NODES / 4, 256, 0, stream>>>(feat0, fA, feat0, offsets, csr_src, csr_ab, inv_buf);
    hop_k<<<N_NODES / 4, 256, 0, stream>>>(fA, fB, feat0, offsets, csr_src, csr_ab, inv_buf);
    hop_k<<<N_NODES / 4, 256, 0, stream>>>(fB, fA, feat0, offsets, csr_src, csr_ab, inv_buf);
    hop_k<<<N_NODES / 4, 256, 0, stream>>>(fA, fB, feat0, offsets, csr_src, csr_ab, inv_buf);
    hop_k<<<N_NODES / 4, 256, 0, stream>>>(fB, fA, feat0, offsets, csr_src, csr_ab, inv_buf);

    // FFN + residuals (MFMA)
    ffn_k<<<N_NODES / 32, 256, 0, stream>>>(fA, h, ln2_g, ln2_b, W1s, b1, W2s, b2,
                                            out);
}